// Round 1
// 4477.081 us; speedup vs baseline: 5.5768x; 5.5768x over previous
//
#include <hip/hip_runtime.h>
#include <stdint.h>

typedef unsigned int uint;
typedef unsigned short ushort;
typedef unsigned long long u64;

#define BATCH 256          // B
#define TLEN  512          // T
#define BT    (BATCH*TLEN) // 131072
#define HID   128
#define G3    384          // 3*HID gate rows
#define GI_R  32           // rows per gi block

// Roles: 0 input,1 hgb,2 stat,3 nnan,4 ttd,5 emb,6 rteW,7 rteb,
// 8 shWih,9 shWhh,10 shbih,11 shbhh, 12..15 t1 Wih/Whh/bih/bhh,
// 16..19 t2 Wih/Whh/bih/bhh, 20 t1w,21 t1wb,22 t2w,23 t2wb.

struct Tab { const void* p[24]; int sz[24]; };

__device__ __forceinline__ float b2f(ushort u) { return __uint_as_float(((uint)u) << 16); }
__device__ __forceinline__ ushort f2b(float f) {            // RTNE fp32->bf16
  uint x = __float_as_uint(f);
  return (ushort)((x + 0x7fffu + ((x >> 16) & 1u)) >> 16);
}
__device__ __forceinline__ float loadf(const void* p, int i, int bf) {
  return bf ? b2f(((const ushort*)p)[i]) : ((const float*)p)[i];
}
// Clamp flushes NaN (fmaxf(c, NaN) == c per IEEE) and Inf -> finite.
__device__ __forceinline__ float sanz(float x) { return fminf(1e4f, fmaxf(-1e4f, x)); }

__device__ __forceinline__ float sigmoidf_(float x) { return 1.0f / (1.0f + __expf(-x)); }
__device__ __forceinline__ float tanhf_(float x) {
  x = fminf(10.0f, fmaxf(-10.0f, x));
  float t = __expf(-2.0f * x);
  return __fdividef(1.0f - t, 1.0f + t);
}

// Unpack bf16x2 + 2 FMA.
__device__ __forceinline__ float dot2(uint w, uint v, float acc) {
  acc = fmaf(__uint_as_float(w << 16), __uint_as_float(v << 16), acc);
  acc = fmaf(__uint_as_float(w & 0xffff0000u), __uint_as_float(v & 0xffff0000u), acc);
  return acc;
}
__device__ __forceinline__ void dot2x4(uint4 w, uint4 v, float& a0, float& a1) {
  a0 = dot2(w.x, v.x, a0);
  a1 = dot2(w.y, v.y, a1);
  a0 = dot2(w.z, v.z, a0);
  a1 = dot2(w.w, v.w, a1);
}
__device__ __forceinline__ float blo(uint u)  { return __uint_as_float(u << 16); }
__device__ __forceinline__ float bhi_(uint u) { return __uint_as_float(u & 0xffff0000u); }

// ---------------------------------------------------------------------------
// K0: on-device input resolution + dtype probes (unchanged).
// ---------------------------------------------------------------------------
__device__ bool emb_ok_dev(const void* q, int bfc) {
  if (q == nullptr) return false;
  if (bfc) {
    const ushort* us = (const ushort*)q;
    float v1 = b2f(us[1]), v10 = b2f(us[10]), v11 = b2f(us[11]);
    return us[0] == 0 && v1 > 0.30f && v1 < 0.33f && v10 > 0.25f && v10 < 0.28f &&
           v11 > 0.16f && v11 < 0.18f;
  } else {
    const float* f = (const float*)q;
    return f[0] == 0.0f && f[1] > 0.31f && f[1] < 0.322f && f[10] > 0.26f &&
           f[10] < 0.272f && f[11] > 0.165f && f[11] < 0.176f;
  }
}

__global__ void detect_kernel(Tab tab, u64* __restrict__ ptab, int* __restrict__ flags) {
  if (threadIdx.x != 0) return;
  const int elems[24] = {3538944,131072,786432,3538944,131072,15000,100,10,
                         26880,49152,384,384,66048,49152,384,384,
                         76416,49152,384,384,128,1,128,1};
  const int sigm[24] = {0,1,2,3,23,4,5,6,7,8,9,10,11,12,13,14,17,18,19,20,15,16,21,22};
  int map[24];
  int bf = -1;
  bool done = false;
  for (int interp = 0; interp < 3 && !done; interp++) {
    int assigned[24];
    for (int r = 0; r < 24; r++) assigned[r] = 0;
    bool ok = true;
    for (int i = 0; i < 24 && ok; i++) {
      bool found = false;
      for (int r = 0; r < 24; r++) {
        int e = elems[r];
        if (interp == 1) e *= (r == 4) ? 4 : 2;
        if (interp == 2) e *= 4;
        if (!assigned[r] && tab.sz[i] == e) { map[r] = i; assigned[r] = 1; found = true; break; }
      }
      if (!found) ok = false;
    }
    if (!ok) continue;
    int bfc = (interp == 0) ? ((((const ushort*)tab.p[map[5]])[1] != 0) ? 1 : 0)
                            : ((interp == 1) ? 1 : 0);
    if (emb_ok_dev(tab.p[map[5]], bfc)) { bf = bfc; done = true; }
  }
  if (!done) {
    const void* q5 = tab.p[5];
    int b5 = (((const ushort*)q5)[1] != 0) ? 1 : 0;
    if (emb_ok_dev(q5, b5)) {
      for (int r = 0; r < 24; r++) map[r] = r;
      bf = b5; done = true;
    }
  }
  if (!done) {
    const void* q4 = tab.p[4];
    int b4 = (((const ushort*)q4)[1] != 0) ? 1 : 0;
    if (emb_ok_dev(q4, b4)) {
      for (int r = 0; r < 24; r++) map[r] = sigm[r];
      bf = b4; done = true;
    }
  }
  if (!done) {
    for (int r = 0; r < 24; r++) map[r] = r;
    bf = (((const ushort*)tab.p[5])[1] != 0) ? 1 : 0;
  }
  for (int r = 0; r < 24; r++) ptab[r] = (u64)tab.p[map[r]];
  flags[0] = bf;
  const void* tq = tab.p[map[4]];
  const int* ti = (const int*)tq;
  const float* tf = (const float*)tq;
  int ok_i = 1, ok_f = 1;
  for (int k = 0; k < 64; k++) {
    int i = k * 16 + 3;
    int vi = ti[i];
    if (vi < 0 || vi >= 1500) ok_i = 0;
    float vf = tf[i];
    if (!(vf >= 0.f && vf < 1500.f && vf == floorf(vf))) ok_f = 0;
  }
  flags[1] = ok_i ? 0 : (ok_f ? 1 : 2);
}

// ---------------------------------------------------------------------------
// K1: tt[b,t,:] = rte_emb[idx] @ rte_W.T + rte_b   (stored canonical bf16)
// ---------------------------------------------------------------------------
__global__ void __launch_bounds__(256) tt_kernel(const u64* __restrict__ ptab,
                                                 const int* __restrict__ flags,
                                                 ushort* __restrict__ tt) {
  const int bf = flags[0];
  const int tmode = flags[1];
  const void* ttd = (const void*)ptab[4];
  const void* emb = (const void*)ptab[5];
  const void* W   = (const void*)ptab[6];
  const void* bb  = (const void*)ptab[7];
  int n = blockIdx.x * blockDim.x + threadIdx.x;
  if (n >= BT) return;
  int idx;
  if (tmode == 0)      idx = ((const int*)ttd)[n];
  else if (tmode == 1) idx = (int)((const float*)ttd)[n];
  else                 idx = (int)b2f(((const ushort*)ttd)[n]);
  if (idx < 0) idx = 0;
  if (idx >= 1500) idx = 1499;
  float e[10];
#pragma unroll
  for (int j = 0; j < 10; j++) e[j] = sanz(loadf(emb, idx * 10 + j, bf));
#pragma unroll
  for (int k = 0; k < 10; k++) {
    float acc = sanz(loadf(bb, k, bf));
#pragma unroll
    for (int j = 0; j < 10; j++) acc = fmaf(e[j], sanz(loadf(W, k * 10 + j, bf)), acc);
    tt[n * 10 + k] = f2b(acc);
  }
}

// ---------------------------------------------------------------------------
// K2a: gi precompute for the SHARED GRU.
// gi[n,g] = bih[g] + sum_d x_sh[n,d]*Wih[g,d];  x_sh = [input27|nnan27|stat6|tt10].
// Block: 384 threads (thread = gate row), GI_R rows staged in LDS.
// ---------------------------------------------------------------------------
__global__ void __launch_bounds__(384, 2) gi_sh_kernel(
    const u64* __restrict__ ptab, const int* __restrict__ flags,
    const ushort* __restrict__ tt, void* __restrict__ gout, int gi32) {
  __shared__ alignas(16) ushort xs[GI_R][72];   // 70 padded to 72 (9 uint4)
  const int bf = flags[0];
  const void* xin  = (const void*)ptab[0];
  const void* stat = (const void*)ptab[2];
  const void* nnan = (const void*)ptab[3];
  const void* Wih  = (const void*)ptab[8];
  const void* bih  = (const void*)ptab[10];
  const int tid = threadIdx.x;
  const int n0 = blockIdx.x * GI_R;

  uint4 w[9];
#pragma unroll
  for (int c = 0; c < 9; c++) {
    uint pk[4];
#pragma unroll
    for (int e = 0; e < 4; e++) {
      int p = c * 4 + e;
      uint lo = (2 * p < 70) ? (uint)f2b(sanz(loadf(Wih, tid * 70 + 2 * p, bf))) : 0u;
      uint hi = (2 * p + 1 < 70) ? (uint)f2b(sanz(loadf(Wih, tid * 70 + 2 * p + 1, bf))) : 0u;
      pk[e] = lo | (hi << 16);
    }
    w[c] = make_uint4(pk[0], pk[1], pk[2], pk[3]);
  }
  const float bi = sanz(loadf(bih, tid, bf));

  for (int idx = tid; idx < GI_R * 72; idx += 384) {
    int r = idx / 72, d = idx % 72;
    int n = n0 + r;
    float v = 0.f;
    if (d < 27)       v = loadf(xin, n * 27 + d, bf);
    else if (d < 54)  v = loadf(nnan, n * 27 + (d - 27), bf);
    else if (d < 60)  v = loadf(stat, n * 6 + (d - 54), bf);
    else if (d < 70)  v = b2f(tt[n * 10 + (d - 60)]);
    xs[r][d] = f2b(sanz(v));
  }
  __syncthreads();

#pragma unroll 1
  for (int r = 0; r < GI_R; r++) {
    const uint4* xr = (const uint4*)xs[r];
    float a0 = 0.f, a1 = 0.f;
#pragma unroll
    for (int c = 0; c < 9; c++) dot2x4(w[c], xr[c], a0, a1);
    float g = a0 + a1 + bi;
    size_t o = (size_t)(n0 + r) * G3 + tid;
    if (gi32) ((float*)gout)[o] = g;
    else      ((ushort*)gout)[o] = f2b(g);
  }
}

// ---------------------------------------------------------------------------
// K2b: gi precompute for the TASK GRUs (t1: DIN=172, t2: DIN=199; pad to 200).
// only: -1 = both (grid 8192, upper half t2), 0 = t1 only, 1 = t2 only.
// ---------------------------------------------------------------------------
__global__ void __launch_bounds__(384, 2) gi_task_kernel(
    const u64* __restrict__ ptab, const int* __restrict__ flags,
    const ushort* __restrict__ hsh, const ushort* __restrict__ tt,
    void* __restrict__ g1, void* __restrict__ g2, int gi32, int only) {
  __shared__ alignas(16) ushort xs[GI_R][200];  // 400B row stride (25 uint4)
  const int bf = flags[0];
  const int is2 = (only < 0) ? (blockIdx.x >= (BT / GI_R)) : only;
  const int n0 = (blockIdx.x & (BT / GI_R - 1)) * GI_R;
  const int DIN = is2 ? 199 : 172;
  const void* xin  = (const void*)ptab[0];
  const void* hgb  = (const void*)ptab[1];
  const void* stat = (const void*)ptab[2];
  const void* nnan = (const void*)ptab[3];
  const void* Wih  = (const void*)ptab[is2 ? 16 : 12];
  const void* bih  = (const void*)ptab[is2 ? 18 : 14];
  void* gout = is2 ? g2 : g1;
  const int tid = threadIdx.x;

  uint4 w[25];
#pragma unroll
  for (int c = 0; c < 25; c++) {
    uint pk[4];
#pragma unroll
    for (int e = 0; e < 4; e++) {
      int p = c * 4 + e;
      uint lo = (2 * p < DIN) ? (uint)f2b(sanz(loadf(Wih, tid * DIN + 2 * p, bf))) : 0u;
      uint hi = (2 * p + 1 < DIN) ? (uint)f2b(sanz(loadf(Wih, tid * DIN + 2 * p + 1, bf))) : 0u;
      pk[e] = lo | (hi << 16);
    }
    w[c] = make_uint4(pk[0], pk[1], pk[2], pk[3]);
  }
  const float bi = sanz(loadf(bih, tid, bf));

  for (int idx = tid; idx < GI_R * 200; idx += 384) {
    int r = idx / 200, d = idx % 200;
    int n = n0 + r;
    float v = 0.f;
    if (d < 128)        v = b2f(hsh[(size_t)n * HID + d]);
    else if (d < 155)   v = loadf(nnan, n * 27 + (d - 128), bf);
    else if (d < 156)   v = loadf(hgb, n, bf);
    else if (is2) {
      if (d < 183)      v = loadf(xin, n * 27 + (d - 156), bf);
      else if (d < 189) v = loadf(stat, n * 6 + (d - 183), bf);
      else if (d < 199) v = b2f(tt[n * 10 + (d - 189)]);
    } else {
      if (d < 162)      v = loadf(stat, n * 6 + (d - 156), bf);
      else if (d < 172) v = b2f(tt[n * 10 + (d - 162)]);
    }
    xs[r][d] = f2b(sanz(v));
  }
  __syncthreads();

#pragma unroll 1
  for (int r = 0; r < GI_R; r++) {
    const uint4* xr = (const uint4*)xs[r];
    float a0 = 0.f, a1 = 0.f;
#pragma unroll
    for (int c = 0; c < 25; c++) dot2x4(w[c], xr[c], a0, a1);
    float g = a0 + a1 + bi;
    size_t o = (size_t)(n0 + r) * G3 + tid;
    if (gi32) ((float*)gout)[o] = g;
    else      ((ushort*)gout)[o] = f2b(g);
  }
}

// ---------------------------------------------------------------------------
// K3: slim recurrent scan. Only Whh (64 VGPRs packed) lives in registers ->
// no spill. h kept fp32 in LDS; gate preactivations read from precomputed gi.
// axis=0: lane = t (shared GRU, scan over b). axis=1: lane = b (task GRUs,
// scan over t); blocks >= BATCH take the "B" parameter set.
// ---------------------------------------------------------------------------
__global__ void __launch_bounds__(384, 3) scan_kernel(
    const u64* __restrict__ ptab, const int* __restrict__ flags,
    const void* __restrict__ gi_0, const void* __restrict__ gi_1, int gi32,
    ushort* __restrict__ out_0, ushort* __restrict__ out_1,
    int whh0, int bhh0, int whh1, int bhh1, int nsteps, int axis) {
  __shared__ alignas(16) float hf[HID];
  __shared__ alignas(16) float Ah[G3];

  const int bf = flags[0];
  const int tid = threadIdx.x;
  const int sel = (axis && blockIdx.x >= BATCH) ? 1 : 0;
  const int lane = axis ? (blockIdx.x & (BATCH - 1)) : blockIdx.x;
  const void* Whh = (const void*)ptab[sel ? whh1 : whh0];
  const void* bhh = (const void*)ptab[sel ? bhh1 : bhh0];
  const void* gi  = sel ? gi_1 : gi_0;
  ushort* hout    = sel ? out_1 : out_0;

  uint4 wh[16];
#pragma unroll
  for (int c = 0; c < 16; c++) {
    uint pk[4];
#pragma unroll
    for (int e = 0; e < 4; e++) {
      int p = c * 4 + e;
      uint lo = (uint)f2b(sanz(loadf(Whh, tid * HID + 2 * p, bf)));
      uint hi = (uint)f2b(sanz(loadf(Whh, tid * HID + 2 * p + 1, bf)));
      pk[e] = lo | (hi << 16);
    }
    wh[c] = make_uint4(pk[0], pk[1], pk[2], pk[3]);
  }
  const float bh = sanz(loadf(bhh, tid, bf));

  if (tid < HID) hf[tid] = 0.f;
  float hprev = 0.f;
  __syncthreads();

#pragma unroll 1
  for (int s = 0; s < nsteps; s++) {
    const int n = axis ? (lane * TLEN + s) : (s * TLEN + lane);
    const size_t base = (size_t)n * G3;
    float gv0 = 0.f, gv1 = 0.f, gv2 = 0.f;
    if (tid < HID) {   // prefetch gate preactivations (independent of h)
      if (gi32) {
        const float* g = (const float*)gi;
        gv0 = g[base + tid]; gv1 = g[base + HID + tid]; gv2 = g[base + 2 * HID + tid];
      } else {
        const ushort* g = (const ushort*)gi;
        gv0 = b2f(g[base + tid]); gv1 = b2f(g[base + HID + tid]); gv2 = b2f(g[base + 2 * HID + tid]);
      }
    }
    // recurrent matvec: bf16 weights (packed) x fp32 h (broadcast LDS reads)
    float a0 = 0.f, a1 = 0.f;
    const float4* h4 = (const float4*)hf;
#pragma unroll
    for (int c = 0; c < 16; c++) {
      uint4 wv = wh[c];
      float4 x0 = h4[2 * c];
      float4 x1 = h4[2 * c + 1];
      a0 = fmaf(blo(wv.x), x0.x, a0); a1 = fmaf(bhi_(wv.x), x0.y, a1);
      a0 = fmaf(blo(wv.y), x0.z, a0); a1 = fmaf(bhi_(wv.y), x0.w, a1);
      a0 = fmaf(blo(wv.z), x1.x, a0); a1 = fmaf(bhi_(wv.z), x1.y, a1);
      a0 = fmaf(blo(wv.w), x1.z, a0); a1 = fmaf(bhi_(wv.w), x1.w, a1);
    }
    Ah[tid] = a0 + a1 + bh;
    __syncthreads();

    if (tid < HID) {
      float r  = sigmoidf_(gv0 + Ah[tid]);
      float z  = sigmoidf_(gv1 + Ah[HID + tid]);
      float nn = tanhf_(gv2 + r * Ah[2 * HID + tid]);
      float h2 = (1.0f - z) * nn + z * hprev;
      hprev = h2;
      hout[(size_t)n * HID + tid] = f2b(h2);
      hf[tid] = h2;
    }
    __syncthreads();   // publish hf before next step's dot
  }
}

// ---------------------------------------------------------------------------
// Legacy monolithic kernels — workspace-starved fallback only (tier 4).
// ---------------------------------------------------------------------------
#define SH_DIN  70
#define SH_DINP 72
#define SH_NP4  9

__global__ void __launch_bounds__(G3) shared_gru_kernel(
    const u64* __restrict__ ptab, const int* __restrict__ flags,
    const ushort* __restrict__ tt, ushort* __restrict__ hsh) {
  __shared__ alignas(16) ushort xs[SH_DINP];
  __shared__ alignas(16) ushort hhi[HID];
  __shared__ alignas(16) ushort hlo[HID];
  __shared__ float Ai[G3];
  __shared__ float Ah[G3];

  const int bf = flags[0];
  const void* xin  = (const void*)ptab[0];
  const void* stat = (const void*)ptab[2];
  const void* nnan = (const void*)ptab[3];
  const void* Wih  = (const void*)ptab[8];
  const void* Whh  = (const void*)ptab[9];
  const void* bih  = (const void*)ptab[10];
  const void* bhh  = (const void*)ptab[11];
  const int tid = threadIdx.x;
  const int t = blockIdx.x;

  uint4 wi4[SH_NP4];
#pragma unroll
  for (int c = 0; c < SH_NP4; c++) {
    uint pk[4];
#pragma unroll
    for (int e = 0; e < 4; e++) {
      int p = c * 4 + e;
      uint lo = (2 * p < SH_DIN) ? (uint)f2b(sanz(loadf(Wih, tid * SH_DIN + 2 * p, bf))) : 0u;
      uint hi = (2 * p + 1 < SH_DIN) ? (uint)f2b(sanz(loadf(Wih, tid * SH_DIN + 2 * p + 1, bf))) : 0u;
      pk[e] = lo | (hi << 16);
    }
    wi4[c] = make_uint4(pk[0], pk[1], pk[2], pk[3]);
  }
  uint4 wh4[16];
#pragma unroll
  for (int c = 0; c < 16; c++) {
    uint pk[4];
#pragma unroll
    for (int e = 0; e < 4; e++) {
      int p = c * 4 + e;
      uint lo = (uint)f2b(sanz(loadf(Whh, tid * HID + 2 * p, bf)));
      uint hi = (uint)f2b(sanz(loadf(Whh, tid * HID + 2 * p + 1, bf)));
      pk[e] = lo | (hi << 16);
    }
    wh4[c] = make_uint4(pk[0], pk[1], pk[2], pk[3]);
  }
  const float bi = sanz(loadf(bih, tid, bf));
  const float bh = sanz(loadf(bhh, tid, bf));

  if (tid < HID) { hhi[tid] = 0; hlo[tid] = 0; }
  if (tid >= SH_DIN && tid < SH_DINP) xs[tid] = 0;
  float hprev = 0.0f;
  __syncthreads();

#pragma unroll 1
  for (int b = 0; b < BATCH; b++) {
    const int n = b * TLEN + t;
    if (tid < SH_DIN) {
      float v;
      if (tid < 27)       v = loadf(xin, n * 27 + tid, bf);
      else if (tid < 54)  v = loadf(nnan, n * 27 + (tid - 27), bf);
      else if (tid < 60)  v = loadf(stat, n * 6 + (tid - 54), bf);
      else                v = b2f(tt[n * 10 + (tid - 60)]);
      xs[tid] = f2b(sanz(v));
    }
    __syncthreads();

    float g0 = bi, g1 = 0.0f;
    const uint4* xs4 = (const uint4*)xs;
#pragma unroll
    for (int c = 0; c < SH_NP4; c++) dot2x4(wi4[c], xs4[c], g0, g1);

    float h0 = bh, h1 = 0.0f;
    const uint4* hh4 = (const uint4*)hhi;
    const uint4* hl4 = (const uint4*)hlo;
#pragma unroll
    for (int c = 0; c < 16; c++) {
      dot2x4(wh4[c], hh4[c], h0, h1);
      dot2x4(wh4[c], hl4[c], h0, h1);
    }
    Ai[tid] = g0 + g1;
    Ah[tid] = h0 + h1;
    __syncthreads();

    if (tid < HID) {
      float r = sigmoidf_(Ai[tid] + Ah[tid]);
      float z = sigmoidf_(Ai[HID + tid] + Ah[HID + tid]);
      float nn = tanhf_(Ai[2 * HID + tid] + r * Ah[2 * HID + tid]);
      float h2 = (1.0f - z) * nn + z * hprev;
      hprev = h2;
      hsh[n * HID + tid] = f2b(h2);
      uint hb = __float_as_uint(h2) & 0xffff0000u;
      hhi[tid] = (ushort)(hb >> 16);
      hlo[tid] = f2b(h2 - __uint_as_float(hb));
    }
  }
}

#define T_DINP 200
#define T_NP4  25

__global__ void __launch_bounds__(G3) task_gru_kernel(
    const u64* __restrict__ ptab, const int* __restrict__ flags,
    const ushort* __restrict__ hsh, const ushort* __restrict__ tt,
    ushort* __restrict__ h1o, ushort* __restrict__ h2o) {
  __shared__ alignas(16) ushort xs[T_DINP];
  __shared__ alignas(16) ushort hhi[HID];
  __shared__ alignas(16) ushort hlo[HID];
  __shared__ float Ai[G3];
  __shared__ float Ah[G3];

  const int bf = flags[0];
  const int tid = threadIdx.x;
  const int is2 = (blockIdx.x >= BATCH) ? 1 : 0;
  const int b = blockIdx.x & (BATCH - 1);
  const int DIN = is2 ? 199 : 172;
  const void* xin  = (const void*)ptab[0];
  const void* hgb  = (const void*)ptab[1];
  const void* stat = (const void*)ptab[2];
  const void* nnan = (const void*)ptab[3];
  const void* Wih  = (const void*)ptab[is2 ? 16 : 12];
  const void* Whh  = (const void*)ptab[is2 ? 17 : 13];
  const void* bihp = (const void*)ptab[is2 ? 18 : 14];
  const void* bhhp = (const void*)ptab[is2 ? 19 : 15];
  ushort* hout = is2 ? h2o : h1o;

  uint4 wi4[T_NP4];
#pragma unroll
  for (int c = 0; c < T_NP4; c++) {
    uint pk[4];
#pragma unroll
    for (int e = 0; e < 4; e++) {
      int p = c * 4 + e;
      uint lo = (2 * p < DIN) ? (uint)f2b(sanz(loadf(Wih, tid * DIN + 2 * p, bf))) : 0u;
      uint hi = (2 * p + 1 < DIN) ? (uint)f2b(sanz(loadf(Wih, tid * DIN + 2 * p + 1, bf))) : 0u;
      pk[e] = lo | (hi << 16);
    }
    wi4[c] = make_uint4(pk[0], pk[1], pk[2], pk[3]);
  }
  uint4 wh4[16];
#pragma unroll
  for (int c = 0; c < 16; c++) {
    uint pk[4];
#pragma unroll
    for (int e = 0; e < 4; e++) {
      int p = c * 4 + e;
      uint lo = (uint)f2b(sanz(loadf(Whh, tid * HID + 2 * p, bf)));
      uint hi = (uint)f2b(sanz(loadf(Whh, tid * HID + 2 * p + 1, bf)));
      pk[e] = lo | (hi << 16);
    }
    wh4[c] = make_uint4(pk[0], pk[1], pk[2], pk[3]);
  }
  const float bi = sanz(loadf(bihp, tid, bf));
  const float bh = sanz(loadf(bhhp, tid, bf));

  if (tid < HID) { hhi[tid] = 0; hlo[tid] = 0; }
  if (tid >= DIN && tid < T_DINP) xs[tid] = 0;
  float hprev = 0.0f;
  __syncthreads();

#pragma unroll 1
  for (int t = 0; t < TLEN; t++) {
    const int n = b * TLEN + t;
    if (tid < DIN) {
      float v;
      if (tid < 128)        v = b2f(hsh[n * HID + tid]);
      else if (tid < 155)   v = loadf(nnan, n * 27 + (tid - 128), bf);
      else if (tid < 156)   v = loadf(hgb, n, bf);
      else if (is2) {
        if (tid < 183)      v = loadf(xin, n * 27 + (tid - 156), bf);
        else if (tid < 189) v = loadf(stat, n * 6 + (tid - 183), bf);
        else                v = b2f(tt[n * 10 + (tid - 189)]);
      } else {
        if (tid < 162)      v = loadf(stat, n * 6 + (tid - 156), bf);
        else                v = b2f(tt[n * 10 + (tid - 162)]);
      }
      xs[tid] = f2b(sanz(v));
    }
    __syncthreads();

    float g0 = bi, g1 = 0.0f;
    const uint4* xs4 = (const uint4*)xs;
#pragma unroll
    for (int c = 0; c < T_NP4; c++) dot2x4(wi4[c], xs4[c], g0, g1);

    float h0 = bh, h1 = 0.0f;
    const uint4* hh4 = (const uint4*)hhi;
    const uint4* hl4 = (const uint4*)hlo;
#pragma unroll
    for (int c = 0; c < 16; c++) {
      dot2x4(wh4[c], hh4[c], h0, h1);
      dot2x4(wh4[c], hl4[c], h0, h1);
    }
    Ai[tid] = g0 + g1;
    Ah[tid] = h0 + h1;
    __syncthreads();

    if (tid < HID) {
      float r = sigmoidf_(Ai[tid] + Ah[tid]);
      float z = sigmoidf_(Ai[HID + tid] + Ah[HID + tid]);
      float nn = tanhf_(Ai[2 * HID + tid] + r * Ah[2 * HID + tid]);
      float h2 = (1.0f - z) * nn + z * hprev;
      hprev = h2;
      hout[n * HID + tid] = f2b(h2);
      uint hb = __float_as_uint(h2) & 0xffff0000u;
      hhi[tid] = (ushort)(hb >> 16);
      hlo[tid] = f2b(h2 - __uint_as_float(hb));
    }
  }
}

// ---------------------------------------------------------------------------
// K4: both prefix attentions in ONE launch (512 blocks). FLOAT32 OUTPUT.
// ---------------------------------------------------------------------------
__global__ void __launch_bounds__(128) attn_kernel(
    const u64* __restrict__ ptab, const int* __restrict__ flags,
    const ushort* __restrict__ h1, const ushort* __restrict__ h2,
    float* __restrict__ outp) {
  __shared__ float pl[TLEN];
  __shared__ alignas(16) uint wp[64];
  __shared__ float red[2];

  const int bf = flags[0];
  const int is2 = (blockIdx.x >= BATCH) ? 1 : 0;
  const int b = blockIdx.x & (BATCH - 1);
  const int tid = threadIdx.x;
  const ushort* h = is2 ? h2 : h1;
  const void* w  = (const void*)ptab[is2 ? 22 : 20];
  const void* wb = (const void*)ptab[is2 ? 23 : 21];
  float* out = outp + (size_t)is2 * BT * HID;

  if (tid < 64) {
    uint lo = (uint)f2b(sanz(loadf(w, 2 * tid, bf)));
    uint hi = (uint)f2b(sanz(loadf(w, 2 * tid + 1, bf)));
    wp[tid] = lo | (hi << 16);
  }
  __syncthreads();
  const float wbf = sanz(loadf(wb, 0, bf));

  float e[4];
  const uint4* wp4 = (const uint4*)wp;
#pragma unroll
  for (int q = 0; q < 4; q++) {
    int j = q * 128 + tid;
    const uint4* hr4 = (const uint4*)(h + (size_t)(b * TLEN + j) * HID);
    float a0 = 0.f, a1 = 0.f;
#pragma unroll
    for (int c = 0; c < 16; c++) {
      uint4 hv = hr4[c];
      uint4 wv = wp4[c];
      a0 = dot2(hv.x, wv.x, a0);
      a1 = dot2(hv.y, wv.y, a1);
      a0 = dot2(hv.z, wv.z, a0);
      a1 = dot2(hv.w, wv.w, a1);
    }
    e[q] = a0 + a1 + wbf;
    pl[j] = e[q];
  }
  float m = fmaxf(fmaxf(e[0], e[1]), fmaxf(e[2], e[3]));
#pragma unroll
  for (int off = 32; off > 0; off >>= 1) m = fmaxf(m, __shfl_down(m, off));
  if ((tid & 63) == 0) red[tid >> 6] = m;
  __syncthreads();
  m = fmaxf(red[0], red[1]);
#pragma unroll
  for (int q = 0; q < 4; q++) {
    int j = q * 128 + tid;
    pl[j] = __expf(pl[j] - m);
  }
  __syncthreads();

  float s = 0.f, acc = 0.f;
  const ushort* hc = h + (size_t)b * TLEN * HID + tid;
  float* oc = out + (size_t)b * TLEN * HID + tid;
#pragma unroll 1
  for (int j = 0; j < TLEN; j++) {
    float pj = pl[j];
    s += pj;
    acc = fmaf(pj, b2f(hc[j * HID]), acc);
    oc[j * HID] = __fdividef(acc, fmaxf(s, 1e-37f));
  }
}

// ---------------------------------------------------------------------------
extern "C" void kernel_launch(void* const* d_in, const int* in_sizes, int n_in,
                              void* d_out, int out_size, void* d_ws, size_t ws_size,
                              hipStream_t stream) {
  (void)out_size;
  Tab tab;
  for (int i = 0; i < 24; i++) {
    tab.p[i] = (i < n_in) ? d_in[i] : nullptr;
    tab.sz[i] = (i < n_in) ? in_sizes[i] : -1;
  }

  // ws layout: ptab (24 x u64) | flags @192 | data @256:
  // tt (BT*10 bf16) | hsh | h1 | h2 (BT*128 bf16 each) | giA [| giB]
  const size_t fixed = 256 + (size_t)BT * 10 * 2 + 3ull * BT * HID * 2;  // ~103MB
  const size_t gif = (size_t)BT * G3 * 4;   // fp32 gi buffer: 201.3MB
  const size_t gib = (size_t)BT * G3 * 2;   // bf16 gi buffer: 100.7MB
  int tier;
  if      (ws_size >= fixed + 2 * gif) tier = 1;  // fp32 gi, tasks in parallel
  else if (ws_size >= fixed + gif)     tier = 2;  // fp32 gi, tasks serialized
  else if (ws_size >= fixed + gib)     tier = 3;  // bf16 gi, tasks serialized
  else if (ws_size >= fixed)           tier = 4;  // legacy monolithic path
  else return;

  u64* ptab   = (u64*)d_ws;
  int* flags  = (int*)((char*)d_ws + 192);
  ushort* tt  = (ushort*)((char*)d_ws + 256);
  ushort* hsh = tt + (size_t)BT * 10;
  ushort* h1  = hsh + (size_t)BT * HID;
  ushort* h2  = h1 + (size_t)BT * HID;
  float* out  = (float*)d_out;

  detect_kernel<<<dim3(1), dim3(64), 0, stream>>>(tab, ptab, flags);
  tt_kernel<<<dim3(BT / 256), dim3(256), 0, stream>>>(ptab, flags, tt);

  if (tier == 4) {
    shared_gru_kernel<<<dim3(TLEN), dim3(G3), 0, stream>>>(ptab, flags, tt, hsh);
    task_gru_kernel<<<dim3(2 * BATCH), dim3(G3), 0, stream>>>(ptab, flags, hsh, tt, h1, h2);
    attn_kernel<<<dim3(2 * BATCH), dim3(128), 0, stream>>>(ptab, flags, h1, h2, out);
    return;
  }

  const int gi32 = (tier <= 2) ? 1 : 0;
  const size_t esz = gi32 ? 4 : 2;
  char* giA = (char*)d_ws + fixed;
  char* giB = giA + (size_t)BT * G3 * esz;  // valid only in tier 1

  // shared GRU: gi -> scan over b (lane = t)
  gi_sh_kernel<<<dim3(BT / GI_R), dim3(G3), 0, stream>>>(ptab, flags, tt, giA, gi32);
  scan_kernel<<<dim3(TLEN), dim3(G3), 0, stream>>>(ptab, flags, giA, giA, gi32,
                                                   hsh, hsh, 9, 11, 9, 11, BATCH, 0);

  if (tier == 1) {
    // both task GRUs: t1 -> giB, t2 -> giA (shared gi is dead now)
    gi_task_kernel<<<dim3(2 * (BT / GI_R)), dim3(G3), 0, stream>>>(
        ptab, flags, hsh, tt, giB, giA, gi32, -1);
    scan_kernel<<<dim3(2 * BATCH), dim3(G3), 0, stream>>>(ptab, flags, giB, giA, gi32,
                                                          h1, h2, 13, 15, 17, 19, TLEN, 1);
  } else {
    gi_task_kernel<<<dim3(BT / GI_R), dim3(G3), 0, stream>>>(
        ptab, flags, hsh, tt, giA, giA, gi32, 0);
    scan_kernel<<<dim3(BATCH), dim3(G3), 0, stream>>>(ptab, flags, giA, giA, gi32,
                                                      h1, h1, 13, 15, 13, 15, TLEN, 1);
    gi_task_kernel<<<dim3(BT / GI_R), dim3(G3), 0, stream>>>(
        ptab, flags, hsh, tt, giA, giA, gi32, 1);
    scan_kernel<<<dim3(BATCH), dim3(G3), 0, stream>>>(ptab, flags, giA, giA, gi32,
                                                      h2, h2, 17, 19, 17, 19, TLEN, 1);
  }
  attn_kernel<<<dim3(2 * BATCH), dim3(128), 0, stream>>>(ptab, flags, h1, h2, out);
}

// Round 2
// 2308.591 us; speedup vs baseline: 10.8151x; 1.9393x over previous
//
#include <hip/hip_runtime.h>
#include <stdint.h>

typedef unsigned int uint;
typedef unsigned short ushort;
typedef unsigned long long u64;

#define BATCH 256          // B
#define TLEN  512          // T
#define BT    (BATCH*TLEN) // 131072
#define HID   128
#define G3    384          // 3*HID gate rows

// Roles: 0 input,1 hgb,2 stat,3 nnan,4 ttd,5 emb,6 rteW,7 rteb,
// 8 shWih,9 shWhh,10 shbih,11 shbhh, 12..15 t1 Wih/Whh/bih/bhh,
// 16..19 t2 Wih/Whh/bih/bhh, 20 t1w,21 t1wb,22 t2w,23 t2wb.

struct Tab { const void* p[24]; int sz[24]; };

typedef __attribute__((ext_vector_type(8))) short bf16x8;
typedef __attribute__((ext_vector_type(4))) float f32x4;

__device__ __forceinline__ float b2f(ushort u) { return __uint_as_float(((uint)u) << 16); }
__device__ __forceinline__ ushort f2b(float f) {            // RTNE fp32->bf16
  uint x = __float_as_uint(f);
  return (ushort)((x + 0x7fffu + ((x >> 16) & 1u)) >> 16);
}
__device__ __forceinline__ float loadf(const void* p, int i, int bf) {
  return bf ? b2f(((const ushort*)p)[i]) : ((const float*)p)[i];
}
// Clamp flushes NaN (fmaxf(c, NaN) == c per IEEE) and Inf -> finite.
__device__ __forceinline__ float sanz(float x) { return fminf(1e4f, fmaxf(-1e4f, x)); }

__device__ __forceinline__ float sigmoidf_(float x) { return 1.0f / (1.0f + __expf(-x)); }
__device__ __forceinline__ float tanhf_(float x) {
  x = fminf(10.0f, fmaxf(-10.0f, x));
  float t = __expf(-2.0f * x);
  return __fdividef(1.0f - t, 1.0f + t);
}

// Unpack bf16x2 + 2 FMA.
__device__ __forceinline__ float dot2(uint w, uint v, float acc) {
  acc = fmaf(__uint_as_float(w << 16), __uint_as_float(v << 16), acc);
  acc = fmaf(__uint_as_float(w & 0xffff0000u), __uint_as_float(v & 0xffff0000u), acc);
  return acc;
}
__device__ __forceinline__ void dot2x4(uint4 w, uint4 v, float& a0, float& a1) {
  a0 = dot2(w.x, v.x, a0);
  a1 = dot2(w.y, v.y, a1);
  a0 = dot2(w.z, v.z, a0);
  a1 = dot2(w.w, v.w, a1);
}
__device__ __forceinline__ float blo(uint u)  { return __uint_as_float(u << 16); }
__device__ __forceinline__ float bhi_(uint u) { return __uint_as_float(u & 0xffff0000u); }

// ---------------------------------------------------------------------------
// K0: on-device input resolution + dtype probes (unchanged).
// ---------------------------------------------------------------------------
__device__ bool emb_ok_dev(const void* q, int bfc) {
  if (q == nullptr) return false;
  if (bfc) {
    const ushort* us = (const ushort*)q;
    float v1 = b2f(us[1]), v10 = b2f(us[10]), v11 = b2f(us[11]);
    return us[0] == 0 && v1 > 0.30f && v1 < 0.33f && v10 > 0.25f && v10 < 0.28f &&
           v11 > 0.16f && v11 < 0.18f;
  } else {
    const float* f = (const float*)q;
    return f[0] == 0.0f && f[1] > 0.31f && f[1] < 0.322f && f[10] > 0.26f &&
           f[10] < 0.272f && f[11] > 0.165f && f[11] < 0.176f;
  }
}

__global__ void detect_kernel(Tab tab, u64* __restrict__ ptab, int* __restrict__ flags) {
  if (threadIdx.x != 0) return;
  const int elems[24] = {3538944,131072,786432,3538944,131072,15000,100,10,
                         26880,49152,384,384,66048,49152,384,384,
                         76416,49152,384,384,128,1,128,1};
  const int sigm[24] = {0,1,2,3,23,4,5,6,7,8,9,10,11,12,13,14,17,18,19,20,15,16,21,22};
  int map[24];
  int bf = -1;
  bool done = false;
  for (int interp = 0; interp < 3 && !done; interp++) {
    int assigned[24];
    for (int r = 0; r < 24; r++) assigned[r] = 0;
    bool ok = true;
    for (int i = 0; i < 24 && ok; i++) {
      bool found = false;
      for (int r = 0; r < 24; r++) {
        int e = elems[r];
        if (interp == 1) e *= (r == 4) ? 4 : 2;
        if (interp == 2) e *= 4;
        if (!assigned[r] && tab.sz[i] == e) { map[r] = i; assigned[r] = 1; found = true; break; }
      }
      if (!found) ok = false;
    }
    if (!ok) continue;
    int bfc = (interp == 0) ? ((((const ushort*)tab.p[map[5]])[1] != 0) ? 1 : 0)
                            : ((interp == 1) ? 1 : 0);
    if (emb_ok_dev(tab.p[map[5]], bfc)) { bf = bfc; done = true; }
  }
  if (!done) {
    const void* q5 = tab.p[5];
    int b5 = (((const ushort*)q5)[1] != 0) ? 1 : 0;
    if (emb_ok_dev(q5, b5)) {
      for (int r = 0; r < 24; r++) map[r] = r;
      bf = b5; done = true;
    }
  }
  if (!done) {
    const void* q4 = tab.p[4];
    int b4 = (((const ushort*)q4)[1] != 0) ? 1 : 0;
    if (emb_ok_dev(q4, b4)) {
      for (int r = 0; r < 24; r++) map[r] = sigm[r];
      bf = b4; done = true;
    }
  }
  if (!done) {
    for (int r = 0; r < 24; r++) map[r] = r;
    bf = (((const ushort*)tab.p[5])[1] != 0) ? 1 : 0;
  }
  for (int r = 0; r < 24; r++) ptab[r] = (u64)tab.p[map[r]];
  flags[0] = bf;
  const void* tq = tab.p[map[4]];
  const int* ti = (const int*)tq;
  const float* tf = (const float*)tq;
  int ok_i = 1, ok_f = 1;
  for (int k = 0; k < 64; k++) {
    int i = k * 16 + 3;
    int vi = ti[i];
    if (vi < 0 || vi >= 1500) ok_i = 0;
    float vf = tf[i];
    if (!(vf >= 0.f && vf < 1500.f && vf == floorf(vf))) ok_f = 0;
  }
  flags[1] = ok_i ? 0 : (ok_f ? 1 : 2);
}

// ---------------------------------------------------------------------------
// K1: tt[b,t,:] = rte_emb[idx] @ rte_W.T + rte_b   (stored canonical bf16)
// ---------------------------------------------------------------------------
__global__ void __launch_bounds__(256) tt_kernel(const u64* __restrict__ ptab,
                                                 const int* __restrict__ flags,
                                                 ushort* __restrict__ tt) {
  const int bf = flags[0];
  const int tmode = flags[1];
  const void* ttd = (const void*)ptab[4];
  const void* emb = (const void*)ptab[5];
  const void* W   = (const void*)ptab[6];
  const void* bb  = (const void*)ptab[7];
  int n = blockIdx.x * blockDim.x + threadIdx.x;
  if (n >= BT) return;
  int idx;
  if (tmode == 0)      idx = ((const int*)ttd)[n];
  else if (tmode == 1) idx = (int)((const float*)ttd)[n];
  else                 idx = (int)b2f(((const ushort*)ttd)[n]);
  if (idx < 0) idx = 0;
  if (idx >= 1500) idx = 1499;
  float e[10];
#pragma unroll
  for (int j = 0; j < 10; j++) e[j] = sanz(loadf(emb, idx * 10 + j, bf));
#pragma unroll
  for (int k = 0; k < 10; k++) {
    float acc = sanz(loadf(bb, k, bf));
#pragma unroll
    for (int j = 0; j < 10; j++) acc = fmaf(e[j], sanz(loadf(W, k * 10 + j, bf)), acc);
    tt[n * 10 + k] = f2b(acc);
  }
}

// ---------------------------------------------------------------------------
// K1b: pack all three Wih matrices to bf16, K zero-padded, 16B-aligned rows;
// pack biases to fp32. Grid 48: blockIdx % 3 = matrix, / 3 = row slice.
// ---------------------------------------------------------------------------
__global__ void __launch_bounds__(256) wpack_kernel(
    const u64* __restrict__ ptab, const int* __restrict__ flags,
    ushort* __restrict__ wp_sh, ushort* __restrict__ wp_t1,
    ushort* __restrict__ wp_t2, float* __restrict__ biasb) {
  const int bf = flags[0];
  const int m = blockIdx.x % 3;
  const int slice = blockIdx.x / 3;        // 0..15
  const int tid = threadIdx.x;
  const void* W  = (const void*)ptab[m == 0 ? 8 : (m == 1 ? 12 : 16)];
  const void* bi = (const void*)ptab[m == 0 ? 10 : (m == 1 ? 14 : 18)];
  const int DIN = m == 0 ? 70 : (m == 1 ? 172 : 199);
  const int KP  = m == 0 ? 96 : (m == 1 ? 192 : 224);
  ushort* dst = m == 0 ? wp_sh : (m == 1 ? wp_t1 : wp_t2);
  const int total = G3 * KP;
  const int per = total / 16;              // divisible for all three KP
  const int lo = slice * per, hi = lo + per;
  for (int idx = lo + tid; idx < hi; idx += 256) {
    int r = idx / KP, k = idx - r * KP;
    float v = (k < DIN) ? sanz(loadf(W, r * DIN + k, bf)) : 0.f;
    dst[idx] = f2b(v);
  }
  if (slice == 0) {
    for (int g = tid; g < G3; g += 256) biasb[m * G3 + g] = sanz(loadf(bi, g, bf));
  }
}

// ---------------------------------------------------------------------------
// K2: MFMA gi GEMM.  gi[n,g] = bih[g] + sum_k X[n,k] * W[g,k].
// Computed as C[M=g][N=n] = Wpack[g,:] x X^T with v_mfma_f32_16x16x32_bf16.
// Verified layouts (m89): A[l&15][(l>>4)*8+j], B[(l>>4)*8+j][l&15],
// C/D: col=l&15, row=(l>>4)*4+j  ->  lane stores float4 of 4 consecutive g.
// Block: 256 thr (4 waves), N-tile 64 rows; wave w owns gates [96w, 96w+96).
// X staged in LDS, row stride KP+8 ushorts (2-way bank aliasing = free).
// MODE: 0=shared(K 70->96), 1=t1(172->192), 2=t2(199->224).
// ---------------------------------------------------------------------------
template <int MODE>
__global__ void __launch_bounds__(256, 2) gi_mfma_kernel(
    const u64* __restrict__ ptab, const int* __restrict__ flags,
    const ushort* __restrict__ tt, const ushort* __restrict__ hsh,
    const ushort* __restrict__ Wp, const float* __restrict__ biasb,
    void* __restrict__ gout, int gi32) {
  constexpr int DIN = MODE == 0 ? 70 : (MODE == 1 ? 172 : 199);
  constexpr int KP  = MODE == 0 ? 96 : (MODE == 1 ? 192 : 224);
  constexpr int STR = KP + 8;   // ushort row stride; 2-way max bank aliasing
  __shared__ alignas(16) ushort xs[64 * STR];
  __shared__ alignas(16) float bls[G3];
  (void)DIN;

  const int bf = flags[0];
  const int tid = threadIdx.x;
  const int n0 = blockIdx.x * 64;
  const void* xin  = (const void*)ptab[0];
  const void* hgb  = (const void*)ptab[1];
  const void* stat = (const void*)ptab[2];
  const void* nnan = (const void*)ptab[3];

  for (int g = tid; g < G3; g += 256) bls[g] = biasb[MODE * G3 + g];

  if (MODE == 0) {
    for (int idx = tid; idx < 64 * KP; idx += 256) {
      int r = idx / KP, d = idx - r * KP;
      int n = n0 + r;
      float v = 0.f;
      if (d < 27)       v = loadf(xin, n * 27 + d, bf);
      else if (d < 54)  v = loadf(nnan, n * 27 + (d - 27), bf);
      else if (d < 60)  v = loadf(stat, n * 6 + (d - 54), bf);
      else if (d < 70)  v = b2f(tt[n * 10 + (d - 60)]);
      xs[r * STR + d] = f2b(sanz(v));
    }
  } else {
    // hsh segment [0,128): canonical bf16 (already sanitized) -> uint4 copy
    for (int idx = tid; idx < 64 * 16; idx += 256) {
      int r = idx >> 4, c = idx & 15;
      uint4 v = ((const uint4*)(hsh + (size_t)(n0 + r) * HID))[c];
      *(uint4*)&xs[r * STR + c * 8] = v;
    }
    constexpr int REM = KP - 128;
    for (int idx = tid; idx < 64 * REM; idx += 256) {
      int r = idx / REM, d = 128 + (idx - r * REM);
      int n = n0 + r;
      float v = 0.f;
      if (d < 155)      v = loadf(nnan, n * 27 + (d - 128), bf);
      else if (d < 156) v = loadf(hgb, n, bf);
      else if (MODE == 2) {
        if (d < 183)      v = loadf(xin, n * 27 + (d - 156), bf);
        else if (d < 189) v = loadf(stat, n * 6 + (d - 183), bf);
        else if (d < 199) v = b2f(tt[n * 10 + (d - 189)]);
      } else {
        if (d < 162)      v = loadf(stat, n * 6 + (d - 156), bf);
        else if (d < 172) v = b2f(tt[n * 10 + (d - 162)]);
      }
      xs[r * STR + d] = f2b(sanz(v));
    }
  }
  __syncthreads();

  const int l  = tid & 63;
  const int wv = tid >> 6;       // wave 0..3
  const int lr = l & 15;
  const int kg = l >> 4;         // 0..3
  const int g0 = wv * 96;

  f32x4 acc[6][4];
#pragma unroll
  for (int mi = 0; mi < 6; mi++) {
    f32x4 bv = *(const f32x4*)&bls[g0 + mi * 16 + kg * 4];
#pragma unroll
    for (int ni = 0; ni < 4; ni++) acc[mi][ni] = bv;
  }

  const ushort* wbase = Wp + (size_t)(g0 + lr) * KP + kg * 8;
#pragma unroll
  for (int ks = 0; ks < KP; ks += 32) {
    bf16x8 av[6], bvv[4];
#pragma unroll
    for (int mi = 0; mi < 6; mi++)
      av[mi] = *(const bf16x8*)(wbase + (size_t)mi * 16 * KP + ks);
#pragma unroll
    for (int ni = 0; ni < 4; ni++)
      bvv[ni] = *(const bf16x8*)&xs[(ni * 16 + lr) * STR + ks + kg * 8];
#pragma unroll
    for (int mi = 0; mi < 6; mi++)
#pragma unroll
      for (int ni = 0; ni < 4; ni++)
        acc[mi][ni] = __builtin_amdgcn_mfma_f32_16x16x32_bf16(
            av[mi], bvv[ni], acc[mi][ni], 0, 0, 0);
  }

#pragma unroll
  for (int ni = 0; ni < 4; ni++) {
    const size_t nrow = (size_t)(n0 + ni * 16 + lr);
    if (gi32) {
      float* gp = (float*)gout + nrow * G3 + g0 + kg * 4;
#pragma unroll
      for (int mi = 0; mi < 6; mi++) *(f32x4*)(gp + mi * 16) = acc[mi][ni];
    } else {
      ushort* gp = (ushort*)gout + nrow * G3 + g0 + kg * 4;
#pragma unroll
      for (int mi = 0; mi < 6; mi++) {
        uint2 pkt;
        pkt.x = (uint)f2b(acc[mi][ni].x) | ((uint)f2b(acc[mi][ni].y) << 16);
        pkt.y = (uint)f2b(acc[mi][ni].z) | ((uint)f2b(acc[mi][ni].w) << 16);
        *(uint2*)(gp + mi * 16) = pkt;
      }
    }
  }
}

// ---------------------------------------------------------------------------
// K3: slim recurrent scan (unchanged). Only Whh packed in registers.
// ---------------------------------------------------------------------------
__global__ void __launch_bounds__(384, 3) scan_kernel(
    const u64* __restrict__ ptab, const int* __restrict__ flags,
    const void* __restrict__ gi_0, const void* __restrict__ gi_1, int gi32,
    ushort* __restrict__ out_0, ushort* __restrict__ out_1,
    int whh0, int bhh0, int whh1, int bhh1, int nsteps, int axis) {
  __shared__ alignas(16) float hf[HID];
  __shared__ alignas(16) float Ah[G3];

  const int bf = flags[0];
  const int tid = threadIdx.x;
  const int sel = (axis && blockIdx.x >= BATCH) ? 1 : 0;
  const int lane = axis ? (blockIdx.x & (BATCH - 1)) : blockIdx.x;
  const void* Whh = (const void*)ptab[sel ? whh1 : whh0];
  const void* bhh = (const void*)ptab[sel ? bhh1 : bhh0];
  const void* gi  = sel ? gi_1 : gi_0;
  ushort* hout    = sel ? out_1 : out_0;

  uint4 wh[16];
#pragma unroll
  for (int c = 0; c < 16; c++) {
    uint pk[4];
#pragma unroll
    for (int e = 0; e < 4; e++) {
      int p = c * 4 + e;
      uint lo = (uint)f2b(sanz(loadf(Whh, tid * HID + 2 * p, bf)));
      uint hi = (uint)f2b(sanz(loadf(Whh, tid * HID + 2 * p + 1, bf)));
      pk[e] = lo | (hi << 16);
    }
    wh[c] = make_uint4(pk[0], pk[1], pk[2], pk[3]);
  }
  const float bh = sanz(loadf(bhh, tid, bf));

  if (tid < HID) hf[tid] = 0.f;
  float hprev = 0.f;
  __syncthreads();

#pragma unroll 1
  for (int s = 0; s < nsteps; s++) {
    const int n = axis ? (lane * TLEN + s) : (s * TLEN + lane);
    const size_t base = (size_t)n * G3;
    float gv0 = 0.f, gv1 = 0.f, gv2 = 0.f;
    if (tid < HID) {   // prefetch gate preactivations (independent of h)
      if (gi32) {
        const float* g = (const float*)gi;
        gv0 = g[base + tid]; gv1 = g[base + HID + tid]; gv2 = g[base + 2 * HID + tid];
      } else {
        const ushort* g = (const ushort*)gi;
        gv0 = b2f(g[base + tid]); gv1 = b2f(g[base + HID + tid]); gv2 = b2f(g[base + 2 * HID + tid]);
      }
    }
    float a0 = 0.f, a1 = 0.f;
    const float4* h4 = (const float4*)hf;
#pragma unroll
    for (int c = 0; c < 16; c++) {
      uint4 wv = wh[c];
      float4 x0 = h4[2 * c];
      float4 x1 = h4[2 * c + 1];
      a0 = fmaf(blo(wv.x), x0.x, a0); a1 = fmaf(bhi_(wv.x), x0.y, a1);
      a0 = fmaf(blo(wv.y), x0.z, a0); a1 = fmaf(bhi_(wv.y), x0.w, a1);
      a0 = fmaf(blo(wv.z), x1.x, a0); a1 = fmaf(bhi_(wv.z), x1.y, a1);
      a0 = fmaf(blo(wv.w), x1.z, a0); a1 = fmaf(bhi_(wv.w), x1.w, a1);
    }
    Ah[tid] = a0 + a1 + bh;
    __syncthreads();

    if (tid < HID) {
      float r  = sigmoidf_(gv0 + Ah[tid]);
      float z  = sigmoidf_(gv1 + Ah[HID + tid]);
      float nn = tanhf_(gv2 + r * Ah[2 * HID + tid]);
      float h2 = (1.0f - z) * nn + z * hprev;
      hprev = h2;
      hout[(size_t)n * HID + tid] = f2b(h2);
      hf[tid] = h2;
    }
    __syncthreads();   // publish hf before next step's dot
  }
}

// ---------------------------------------------------------------------------
// Legacy monolithic kernels — workspace-starved fallback only (tier 4).
// ---------------------------------------------------------------------------
#define SH_DIN  70
#define SH_DINP 72
#define SH_NP4  9

__global__ void __launch_bounds__(G3) shared_gru_kernel(
    const u64* __restrict__ ptab, const int* __restrict__ flags,
    const ushort* __restrict__ tt, ushort* __restrict__ hsh) {
  __shared__ alignas(16) ushort xs[SH_DINP];
  __shared__ alignas(16) ushort hhi[HID];
  __shared__ alignas(16) ushort hlo[HID];
  __shared__ float Ai[G3];
  __shared__ float Ah[G3];

  const int bf = flags[0];
  const void* xin  = (const void*)ptab[0];
  const void* stat = (const void*)ptab[2];
  const void* nnan = (const void*)ptab[3];
  const void* Wih  = (const void*)ptab[8];
  const void* Whh  = (const void*)ptab[9];
  const void* bih  = (const void*)ptab[10];
  const void* bhh  = (const void*)ptab[11];
  const int tid = threadIdx.x;
  const int t = blockIdx.x;

  uint4 wi4[SH_NP4];
#pragma unroll
  for (int c = 0; c < SH_NP4; c++) {
    uint pk[4];
#pragma unroll
    for (int e = 0; e < 4; e++) {
      int p = c * 4 + e;
      uint lo = (2 * p < SH_DIN) ? (uint)f2b(sanz(loadf(Wih, tid * SH_DIN + 2 * p, bf))) : 0u;
      uint hi = (2 * p + 1 < SH_DIN) ? (uint)f2b(sanz(loadf(Wih, tid * SH_DIN + 2 * p + 1, bf))) : 0u;
      pk[e] = lo | (hi << 16);
    }
    wi4[c] = make_uint4(pk[0], pk[1], pk[2], pk[3]);
  }
  uint4 wh4[16];
#pragma unroll
  for (int c = 0; c < 16; c++) {
    uint pk[4];
#pragma unroll
    for (int e = 0; e < 4; e++) {
      int p = c * 4 + e;
      uint lo = (uint)f2b(sanz(loadf(Whh, tid * HID + 2 * p, bf)));
      uint hi = (uint)f2b(sanz(loadf(Whh, tid * HID + 2 * p + 1, bf)));
      pk[e] = lo | (hi << 16);
    }
    wh4[c] = make_uint4(pk[0], pk[1], pk[2], pk[3]);
  }
  const float bi = sanz(loadf(bih, tid, bf));
  const float bh = sanz(loadf(bhh, tid, bf));

  if (tid < HID) { hhi[tid] = 0; hlo[tid] = 0; }
  if (tid >= SH_DIN && tid < SH_DINP) xs[tid] = 0;
  float hprev = 0.0f;
  __syncthreads();

#pragma unroll 1
  for (int b = 0; b < BATCH; b++) {
    const int n = b * TLEN + t;
    if (tid < SH_DIN) {
      float v;
      if (tid < 27)       v = loadf(xin, n * 27 + tid, bf);
      else if (tid < 54)  v = loadf(nnan, n * 27 + (tid - 27), bf);
      else if (tid < 60)  v = loadf(stat, n * 6 + (tid - 54), bf);
      else                v = b2f(tt[n * 10 + (tid - 60)]);
      xs[tid] = f2b(sanz(v));
    }
    __syncthreads();

    float g0 = bi, g1 = 0.0f;
    const uint4* xs4 = (const uint4*)xs;
#pragma unroll
    for (int c = 0; c < SH_NP4; c++) dot2x4(wi4[c], xs4[c], g0, g1);

    float h0 = bh, h1 = 0.0f;
    const uint4* hh4 = (const uint4*)hhi;
    const uint4* hl4 = (const uint4*)hlo;
#pragma unroll
    for (int c = 0; c < 16; c++) {
      dot2x4(wh4[c], hh4[c], h0, h1);
      dot2x4(wh4[c], hl4[c], h0, h1);
    }
    Ai[tid] = g0 + g1;
    Ah[tid] = h0 + h1;
    __syncthreads();

    if (tid < HID) {
      float r = sigmoidf_(Ai[tid] + Ah[tid]);
      float z = sigmoidf_(Ai[HID + tid] + Ah[HID + tid]);
      float nn = tanhf_(Ai[2 * HID + tid] + r * Ah[2 * HID + tid]);
      float h2 = (1.0f - z) * nn + z * hprev;
      hprev = h2;
      hsh[n * HID + tid] = f2b(h2);
      uint hb = __float_as_uint(h2) & 0xffff0000u;
      hhi[tid] = (ushort)(hb >> 16);
      hlo[tid] = f2b(h2 - __uint_as_float(hb));
    }
  }
}

#define T_DINP 200
#define T_NP4  25

__global__ void __launch_bounds__(G3) task_gru_kernel(
    const u64* __restrict__ ptab, const int* __restrict__ flags,
    const ushort* __restrict__ hsh, const ushort* __restrict__ tt,
    ushort* __restrict__ h1o, ushort* __restrict__ h2o) {
  __shared__ alignas(16) ushort xs[T_DINP];
  __shared__ alignas(16) ushort hhi[HID];
  __shared__ alignas(16) ushort hlo[HID];
  __shared__ float Ai[G3];
  __shared__ float Ah[G3];

  const int bf = flags[0];
  const int tid = threadIdx.x;
  const int is2 = (blockIdx.x >= BATCH) ? 1 : 0;
  const int b = blockIdx.x & (BATCH - 1);
  const int DIN = is2 ? 199 : 172;
  const void* xin  = (const void*)ptab[0];
  const void* hgb  = (const void*)ptab[1];
  const void* stat = (const void*)ptab[2];
  const void* nnan = (const void*)ptab[3];
  const void* Wih  = (const void*)ptab[is2 ? 16 : 12];
  const void* Whh  = (const void*)ptab[is2 ? 17 : 13];
  const void* bihp = (const void*)ptab[is2 ? 18 : 14];
  const void* bhhp = (const void*)ptab[is2 ? 19 : 15];
  ushort* hout = is2 ? h2o : h1o;

  uint4 wi4[T_NP4];
#pragma unroll
  for (int c = 0; c < T_NP4; c++) {
    uint pk[4];
#pragma unroll
    for (int e = 0; e < 4; e++) {
      int p = c * 4 + e;
      uint lo = (2 * p < DIN) ? (uint)f2b(sanz(loadf(Wih, tid * DIN + 2 * p, bf))) : 0u;
      uint hi = (2 * p + 1 < DIN) ? (uint)f2b(sanz(loadf(Wih, tid * DIN + 2 * p + 1, bf))) : 0u;
      pk[e] = lo | (hi << 16);
    }
    wi4[c] = make_uint4(pk[0], pk[1], pk[2], pk[3]);
  }
  uint4 wh4[16];
#pragma unroll
  for (int c = 0; c < 16; c++) {
    uint pk[4];
#pragma unroll
    for (int e = 0; e < 4; e++) {
      int p = c * 4 + e;
      uint lo = (uint)f2b(sanz(loadf(Whh, tid * HID + 2 * p, bf)));
      uint hi = (uint)f2b(sanz(loadf(Whh, tid * HID + 2 * p + 1, bf)));
      pk[e] = lo | (hi << 16);
    }
    wh4[c] = make_uint4(pk[0], pk[1], pk[2], pk[3]);
  }
  const float bi = sanz(loadf(bihp, tid, bf));
  const float bh = sanz(loadf(bhhp, tid, bf));

  if (tid < HID) { hhi[tid] = 0; hlo[tid] = 0; }
  if (tid >= DIN && tid < T_DINP) xs[tid] = 0;
  float hprev = 0.0f;
  __syncthreads();

#pragma unroll 1
  for (int t = 0; t < TLEN; t++) {
    const int n = b * TLEN + t;
    if (tid < DIN) {
      float v;
      if (tid < 128)        v = b2f(hsh[n * HID + tid]);
      else if (tid < 155)   v = loadf(nnan, n * 27 + (tid - 128), bf);
      else if (tid < 156)   v = loadf(hgb, n, bf);
      else if (is2) {
        if (tid < 183)      v = loadf(xin, n * 27 + (tid - 156), bf);
        else if (tid < 189) v = loadf(stat, n * 6 + (tid - 183), bf);
        else                v = b2f(tt[n * 10 + (tid - 189)]);
      } else {
        if (tid < 162)      v = loadf(stat, n * 6 + (tid - 156), bf);
        else                v = b2f(tt[n * 10 + (tid - 162)]);
      }
      xs[tid] = f2b(sanz(v));
    }
    __syncthreads();

    float g0 = bi, g1 = 0.0f;
    const uint4* xs4 = (const uint4*)xs;
#pragma unroll
    for (int c = 0; c < T_NP4; c++) dot2x4(wi4[c], xs4[c], g0, g1);

    float h0 = bh, h1 = 0.0f;
    const uint4* hh4 = (const uint4*)hhi;
    const uint4* hl4 = (const uint4*)hlo;
#pragma unroll
    for (int c = 0; c < 16; c++) {
      dot2x4(wh4[c], hh4[c], h0, h1);
      dot2x4(wh4[c], hl4[c], h0, h1);
    }
    Ai[tid] = g0 + g1;
    Ah[tid] = h0 + h1;
    __syncthreads();

    if (tid < HID) {
      float r = sigmoidf_(Ai[tid] + Ah[tid]);
      float z = sigmoidf_(Ai[HID + tid] + Ah[HID + tid]);
      float nn = tanhf_(Ai[2 * HID + tid] + r * Ah[2 * HID + tid]);
      float h2 = (1.0f - z) * nn + z * hprev;
      hprev = h2;
      hout[n * HID + tid] = f2b(h2);
      uint hb = __float_as_uint(h2) & 0xffff0000u;
      hhi[tid] = (ushort)(hb >> 16);
      hlo[tid] = f2b(h2 - __uint_as_float(hb));
    }
  }
}

// ---------------------------------------------------------------------------
// K4: both prefix attentions in ONE launch (512 blocks). FLOAT32 OUTPUT.
// ---------------------------------------------------------------------------
__global__ void __launch_bounds__(128) attn_kernel(
    const u64* __restrict__ ptab, const int* __restrict__ flags,
    const ushort* __restrict__ h1, const ushort* __restrict__ h2,
    float* __restrict__ outp) {
  __shared__ float pl[TLEN];
  __shared__ alignas(16) uint wp[64];
  __shared__ float red[2];

  const int bf = flags[0];
  const int is2 = (blockIdx.x >= BATCH) ? 1 : 0;
  const int b = blockIdx.x & (BATCH - 1);
  const int tid = threadIdx.x;
  const ushort* h = is2 ? h2 : h1;
  const void* w  = (const void*)ptab[is2 ? 22 : 20];
  const void* wb = (const void*)ptab[is2 ? 23 : 21];
  float* out = outp + (size_t)is2 * BT * HID;

  if (tid < 64) {
    uint lo = (uint)f2b(sanz(loadf(w, 2 * tid, bf)));
    uint hi = (uint)f2b(sanz(loadf(w, 2 * tid + 1, bf)));
    wp[tid] = lo | (hi << 16);
  }
  __syncthreads();
  const float wbf = sanz(loadf(wb, 0, bf));

  float e[4];
  const uint4* wp4 = (const uint4*)wp;
#pragma unroll
  for (int q = 0; q < 4; q++) {
    int j = q * 128 + tid;
    const uint4* hr4 = (const uint4*)(h + (size_t)(b * TLEN + j) * HID);
    float a0 = 0.f, a1 = 0.f;
#pragma unroll
    for (int c = 0; c < 16; c++) {
      uint4 hv = hr4[c];
      uint4 wv = wp4[c];
      a0 = dot2(hv.x, wv.x, a0);
      a1 = dot2(hv.y, wv.y, a1);
      a0 = dot2(hv.z, wv.z, a0);
      a1 = dot2(hv.w, wv.w, a1);
    }
    e[q] = a0 + a1 + wbf;
    pl[j] = e[q];
  }
  float m = fmaxf(fmaxf(e[0], e[1]), fmaxf(e[2], e[3]));
#pragma unroll
  for (int off = 32; off > 0; off >>= 1) m = fmaxf(m, __shfl_down(m, off));
  if ((tid & 63) == 0) red[tid >> 6] = m;
  __syncthreads();
  m = fmaxf(red[0], red[1]);
#pragma unroll
  for (int q = 0; q < 4; q++) {
    int j = q * 128 + tid;
    pl[j] = __expf(pl[j] - m);
  }
  __syncthreads();

  float s = 0.f, acc = 0.f;
  const ushort* hc = h + (size_t)b * TLEN * HID + tid;
  float* oc = out + (size_t)b * TLEN * HID + tid;
#pragma unroll 1
  for (int j = 0; j < TLEN; j++) {
    float pj = pl[j];
    s += pj;
    acc = fmaf(pj, b2f(hc[j * HID]), acc);
    oc[j * HID] = __fdividef(acc, fmaxf(s, 1e-37f));
  }
}

// ---------------------------------------------------------------------------
extern "C" void kernel_launch(void* const* d_in, const int* in_sizes, int n_in,
                              void* d_out, int out_size, void* d_ws, size_t ws_size,
                              hipStream_t stream) {
  (void)out_size;
  Tab tab;
  for (int i = 0; i < 24; i++) {
    tab.p[i] = (i < n_in) ? d_in[i] : nullptr;
    tab.sz[i] = (i < n_in) ? in_sizes[i] : -1;
  }

  // ws layout: ptab(192) | flags @192 | @256: wp_sh(73728) | wp_t1(147456) |
  //            wp_t2(172032) | bias(4608) | tt | hsh | h1 | h2 | giA [| giB]
  const size_t WPSH = (size_t)G3 * 96 * 2;    // 73728
  const size_t WPT1 = (size_t)G3 * 192 * 2;   // 147456
  const size_t WPT2 = (size_t)G3 * 224 * 2;   // 172032
  const size_t BIAS = 3 * G3 * 4;             // 4608
  const size_t packo = 256;
  const size_t datao = packo + WPSH + WPT1 + WPT2 + BIAS;  // 398080
  const size_t fixed = datao + (size_t)BT * 10 * 2 + 3ull * BT * HID * 2;
  const size_t gif = (size_t)BT * G3 * 4;   // fp32 gi buffer: 201.3MB
  const size_t gib = (size_t)BT * G3 * 2;   // bf16 gi buffer: 100.7MB
  int tier;
  if      (ws_size >= fixed + 2 * gif) tier = 1;  // fp32 gi, tasks in parallel
  else if (ws_size >= fixed + gif)     tier = 2;  // fp32 gi, tasks serialized
  else if (ws_size >= fixed + gib)     tier = 3;  // bf16 gi, tasks serialized
  else if (ws_size >= fixed)           tier = 4;  // legacy monolithic path
  else return;

  u64* ptab    = (u64*)d_ws;
  int* flags   = (int*)((char*)d_ws + 192);
  ushort* wpsh = (ushort*)((char*)d_ws + packo);
  ushort* wpt1 = (ushort*)((char*)d_ws + packo + WPSH);
  ushort* wpt2 = (ushort*)((char*)d_ws + packo + WPSH + WPT1);
  float* biasb = (float*)((char*)d_ws + packo + WPSH + WPT1 + WPT2);
  ushort* tt   = (ushort*)((char*)d_ws + datao);
  ushort* hsh  = tt + (size_t)BT * 10;
  ushort* h1   = hsh + (size_t)BT * HID;
  ushort* h2   = h1 + (size_t)BT * HID;
  float* out   = (float*)d_out;

  detect_kernel<<<dim3(1), dim3(64), 0, stream>>>(tab, ptab, flags);
  tt_kernel<<<dim3(BT / 256), dim3(256), 0, stream>>>(ptab, flags, tt);

  if (tier == 4) {
    shared_gru_kernel<<<dim3(TLEN), dim3(G3), 0, stream>>>(ptab, flags, tt, hsh);
    task_gru_kernel<<<dim3(2 * BATCH), dim3(G3), 0, stream>>>(ptab, flags, hsh, tt, h1, h2);
    attn_kernel<<<dim3(2 * BATCH), dim3(128), 0, stream>>>(ptab, flags, h1, h2, out);
    return;
  }

  wpack_kernel<<<dim3(48), dim3(256), 0, stream>>>(ptab, flags, wpsh, wpt1, wpt2, biasb);

  const int gi32 = (tier <= 2) ? 1 : 0;
  const size_t esz = gi32 ? 4 : 2;
  char* giA = (char*)d_ws + fixed;
  char* giB = giA + (size_t)BT * G3 * esz;  // valid only in tier 1

  // shared GRU: MFMA gi -> scan over b (lane = t)
  gi_mfma_kernel<0><<<dim3(BT / 64), dim3(256), 0, stream>>>(
      ptab, flags, tt, hsh, wpsh, biasb, giA, gi32);
  scan_kernel<<<dim3(TLEN), dim3(G3), 0, stream>>>(ptab, flags, giA, giA, gi32,
                                                   hsh, hsh, 9, 11, 9, 11, BATCH, 0);

  if (tier == 1) {
    gi_mfma_kernel<1><<<dim3(BT / 64), dim3(256), 0, stream>>>(
        ptab, flags, tt, hsh, wpt1, biasb, giB, gi32);
    gi_mfma_kernel<2><<<dim3(BT / 64), dim3(256), 0, stream>>>(
        ptab, flags, tt, hsh, wpt2, biasb, giA, gi32);
    scan_kernel<<<dim3(2 * BATCH), dim3(G3), 0, stream>>>(ptab, flags, giB, giA, gi32,
                                                          h1, h2, 13, 15, 17, 19, TLEN, 1);
  } else {
    gi_mfma_kernel<1><<<dim3(BT / 64), dim3(256), 0, stream>>>(
        ptab, flags, tt, hsh, wpt1, biasb, giA, gi32);
    scan_kernel<<<dim3(BATCH), dim3(G3), 0, stream>>>(ptab, flags, giA, giA, gi32,
                                                      h1, h1, 13, 15, 13, 15, TLEN, 1);
    gi_mfma_kernel<2><<<dim3(BT / 64), dim3(256), 0, stream>>>(
        ptab, flags, tt, hsh, wpt2, biasb, giA, gi32);
    scan_kernel<<<dim3(BATCH), dim3(G3), 0, stream>>>(ptab, flags, giA, giA, gi32,
                                                      h2, h2, 17, 19, 17, 19, TLEN, 1);
  }
  attn_kernel<<<dim3(2 * BATCH), dim3(128), 0, stream>>>(ptab, flags, h1, h2, out);
}

// Round 3
// 2198.235 us; speedup vs baseline: 11.3580x; 1.0502x over previous
//
#include <hip/hip_runtime.h>
#include <stdint.h>

typedef unsigned int uint;
typedef unsigned short ushort;
typedef unsigned long long u64;

#define BATCH 256          // B
#define TLEN  512          // T
#define BT    (BATCH*TLEN) // 131072
#define HID   128
#define G3    384          // 3*HID gate rows

// Roles: 0 input,1 hgb,2 stat,3 nnan,4 ttd,5 emb,6 rteW,7 rteb,
// 8 shWih,9 shWhh,10 shbih,11 shbhh, 12..15 t1 Wih/Whh/bih/bhh,
// 16..19 t2 Wih/Whh/bih/bhh, 20 t1w,21 t1wb,22 t2w,23 t2wb.

struct Tab { const void* p[24]; int sz[24]; };

typedef __attribute__((ext_vector_type(8))) short bf16x8;
typedef __attribute__((ext_vector_type(4))) float f32x4;
typedef __attribute__((ext_vector_type(4))) ushort u16x4;

__device__ __forceinline__ float b2f(ushort u) { return __uint_as_float(((uint)u) << 16); }
__device__ __forceinline__ ushort f2b(float f) {            // RTNE fp32->bf16
  uint x = __float_as_uint(f);
  return (ushort)((x + 0x7fffu + ((x >> 16) & 1u)) >> 16);
}
__device__ __forceinline__ float loadf(const void* p, int i, int bf) {
  return bf ? b2f(((const ushort*)p)[i]) : ((const float*)p)[i];
}
// Clamp flushes NaN (fmaxf(c, NaN) == c per IEEE) and Inf -> finite.
__device__ __forceinline__ float sanz(float x) { return fminf(1e4f, fmaxf(-1e4f, x)); }

__device__ __forceinline__ float sigmoidf_(float x) { return 1.0f / (1.0f + __expf(-x)); }
__device__ __forceinline__ float tanhf_(float x) {
  x = fminf(10.0f, fmaxf(-10.0f, x));
  float t = __expf(-2.0f * x);
  return __fdividef(1.0f - t, 1.0f + t);
}

// Unpack bf16x2 + 2 FMA.
__device__ __forceinline__ float dot2(uint w, uint v, float acc) {
  acc = fmaf(__uint_as_float(w << 16), __uint_as_float(v << 16), acc);
  acc = fmaf(__uint_as_float(w & 0xffff0000u), __uint_as_float(v & 0xffff0000u), acc);
  return acc;
}
__device__ __forceinline__ void dot2x4(uint4 w, uint4 v, float& a0, float& a1) {
  a0 = dot2(w.x, v.x, a0);
  a1 = dot2(w.y, v.y, a1);
  a0 = dot2(w.z, v.z, a0);
  a1 = dot2(w.w, v.w, a1);
}

// ---------------------------------------------------------------------------
// K0: on-device input resolution + dtype probes (unchanged).
// ---------------------------------------------------------------------------
__device__ bool emb_ok_dev(const void* q, int bfc) {
  if (q == nullptr) return false;
  if (bfc) {
    const ushort* us = (const ushort*)q;
    float v1 = b2f(us[1]), v10 = b2f(us[10]), v11 = b2f(us[11]);
    return us[0] == 0 && v1 > 0.30f && v1 < 0.33f && v10 > 0.25f && v10 < 0.28f &&
           v11 > 0.16f && v11 < 0.18f;
  } else {
    const float* f = (const float*)q;
    return f[0] == 0.0f && f[1] > 0.31f && f[1] < 0.322f && f[10] > 0.26f &&
           f[10] < 0.272f && f[11] > 0.165f && f[11] < 0.176f;
  }
}

__global__ void detect_kernel(Tab tab, u64* __restrict__ ptab, int* __restrict__ flags) {
  if (threadIdx.x != 0) return;
  const int elems[24] = {3538944,131072,786432,3538944,131072,15000,100,10,
                         26880,49152,384,384,66048,49152,384,384,
                         76416,49152,384,384,128,1,128,1};
  const int sigm[24] = {0,1,2,3,23,4,5,6,7,8,9,10,11,12,13,14,17,18,19,20,15,16,21,22};
  int map[24];
  int bf = -1;
  bool done = false;
  for (int interp = 0; interp < 3 && !done; interp++) {
    int assigned[24];
    for (int r = 0; r < 24; r++) assigned[r] = 0;
    bool ok = true;
    for (int i = 0; i < 24 && ok; i++) {
      bool found = false;
      for (int r = 0; r < 24; r++) {
        int e = elems[r];
        if (interp == 1) e *= (r == 4) ? 4 : 2;
        if (interp == 2) e *= 4;
        if (!assigned[r] && tab.sz[i] == e) { map[r] = i; assigned[r] = 1; found = true; break; }
      }
      if (!found) ok = false;
    }
    if (!ok) continue;
    int bfc = (interp == 0) ? ((((const ushort*)tab.p[map[5]])[1] != 0) ? 1 : 0)
                            : ((interp == 1) ? 1 : 0);
    if (emb_ok_dev(tab.p[map[5]], bfc)) { bf = bfc; done = true; }
  }
  if (!done) {
    const void* q5 = tab.p[5];
    int b5 = (((const ushort*)q5)[1] != 0) ? 1 : 0;
    if (emb_ok_dev(q5, b5)) {
      for (int r = 0; r < 24; r++) map[r] = r;
      bf = b5; done = true;
    }
  }
  if (!done) {
    const void* q4 = tab.p[4];
    int b4 = (((const ushort*)q4)[1] != 0) ? 1 : 0;
    if (emb_ok_dev(q4, b4)) {
      for (int r = 0; r < 24; r++) map[r] = sigm[r];
      bf = b4; done = true;
    }
  }
  if (!done) {
    for (int r = 0; r < 24; r++) map[r] = r;
    bf = (((const ushort*)tab.p[5])[1] != 0) ? 1 : 0;
  }
  for (int r = 0; r < 24; r++) ptab[r] = (u64)tab.p[map[r]];
  flags[0] = bf;
  const void* tq = tab.p[map[4]];
  const int* ti = (const int*)tq;
  const float* tf = (const float*)tq;
  int ok_i = 1, ok_f = 1;
  for (int k = 0; k < 64; k++) {
    int i = k * 16 + 3;
    int vi = ti[i];
    if (vi < 0 || vi >= 1500) ok_i = 0;
    float vf = tf[i];
    if (!(vf >= 0.f && vf < 1500.f && vf == floorf(vf))) ok_f = 0;
  }
  flags[1] = ok_i ? 0 : (ok_f ? 1 : 2);
}

// ---------------------------------------------------------------------------
// K1: tt[b,t,:] = rte_emb[idx] @ rte_W.T + rte_b   (stored canonical bf16)
// ---------------------------------------------------------------------------
__global__ void __launch_bounds__(256) tt_kernel(const u64* __restrict__ ptab,
                                                 const int* __restrict__ flags,
                                                 ushort* __restrict__ tt) {
  const int bf = flags[0];
  const int tmode = flags[1];
  const void* ttd = (const void*)ptab[4];
  const void* emb = (const void*)ptab[5];
  const void* W   = (const void*)ptab[6];
  const void* bb  = (const void*)ptab[7];
  int n = blockIdx.x * blockDim.x + threadIdx.x;
  if (n >= BT) return;
  int idx;
  if (tmode == 0)      idx = ((const int*)ttd)[n];
  else if (tmode == 1) idx = (int)((const float*)ttd)[n];
  else                 idx = (int)b2f(((const ushort*)ttd)[n]);
  if (idx < 0) idx = 0;
  if (idx >= 1500) idx = 1499;
  float e[10];
#pragma unroll
  for (int j = 0; j < 10; j++) e[j] = sanz(loadf(emb, idx * 10 + j, bf));
#pragma unroll
  for (int k = 0; k < 10; k++) {
    float acc = sanz(loadf(bb, k, bf));
#pragma unroll
    for (int j = 0; j < 10; j++) acc = fmaf(e[j], sanz(loadf(W, k * 10 + j, bf)), acc);
    tt[n * 10 + k] = f2b(acc);
  }
}

// ---------------------------------------------------------------------------
// K1b: pack all three Wih matrices to bf16, K zero-padded, 16B-aligned rows;
// pack biases to fp32. Grid 48: blockIdx % 3 = matrix, / 3 = row slice.
// ---------------------------------------------------------------------------
__global__ void __launch_bounds__(256) wpack_kernel(
    const u64* __restrict__ ptab, const int* __restrict__ flags,
    ushort* __restrict__ wp_sh, ushort* __restrict__ wp_t1,
    ushort* __restrict__ wp_t2, float* __restrict__ biasb) {
  const int bf = flags[0];
  const int m = blockIdx.x % 3;
  const int slice = blockIdx.x / 3;        // 0..15
  const int tid = threadIdx.x;
  const void* W  = (const void*)ptab[m == 0 ? 8 : (m == 1 ? 12 : 16)];
  const void* bi = (const void*)ptab[m == 0 ? 10 : (m == 1 ? 14 : 18)];
  const int DIN = m == 0 ? 70 : (m == 1 ? 172 : 199);
  const int KP  = m == 0 ? 96 : (m == 1 ? 192 : 224);
  ushort* dst = m == 0 ? wp_sh : (m == 1 ? wp_t1 : wp_t2);
  const int total = G3 * KP;
  const int per = total / 16;              // divisible for all three KP
  const int lo = slice * per, hi = lo + per;
  for (int idx = lo + tid; idx < hi; idx += 256) {
    int r = idx / KP, k = idx - r * KP;
    float v = (k < DIN) ? sanz(loadf(W, r * DIN + k, bf)) : 0.f;
    dst[idx] = f2b(v);
  }
  if (slice == 0) {
    for (int g = tid; g < G3; g += 256) biasb[m * G3 + g] = sanz(loadf(bi, g, bf));
  }
}

// ---------------------------------------------------------------------------
// K2: MFMA gi GEMM.  gi[n,g] = bih[g] + sum_k X[n,k] * W[g,k].
// C[M=g][N=n] = Wpack[g,:] x X^T with v_mfma_f32_16x16x32_bf16 (m89 layouts).
// ---------------------------------------------------------------------------
template <int MODE>
__global__ void __launch_bounds__(256, 2) gi_mfma_kernel(
    const u64* __restrict__ ptab, const int* __restrict__ flags,
    const ushort* __restrict__ tt, const ushort* __restrict__ hsh,
    const ushort* __restrict__ Wp, const float* __restrict__ biasb,
    void* __restrict__ gout, int gi32) {
  constexpr int DIN = MODE == 0 ? 70 : (MODE == 1 ? 172 : 199);
  constexpr int KP  = MODE == 0 ? 96 : (MODE == 1 ? 192 : 224);
  constexpr int STR = KP + 8;   // ushort row stride; 2-way max bank aliasing
  __shared__ alignas(16) ushort xs[64 * STR];
  __shared__ alignas(16) float bls[G3];
  (void)DIN;

  const int bf = flags[0];
  const int tid = threadIdx.x;
  const int n0 = blockIdx.x * 64;
  const void* xin  = (const void*)ptab[0];
  const void* hgb  = (const void*)ptab[1];
  const void* stat = (const void*)ptab[2];
  const void* nnan = (const void*)ptab[3];

  for (int g = tid; g < G3; g += 256) bls[g] = biasb[MODE * G3 + g];

  if (MODE == 0) {
    for (int idx = tid; idx < 64 * KP; idx += 256) {
      int r = idx / KP, d = idx - r * KP;
      int n = n0 + r;
      float v = 0.f;
      if (d < 27)       v = loadf(xin, n * 27 + d, bf);
      else if (d < 54)  v = loadf(nnan, n * 27 + (d - 27), bf);
      else if (d < 60)  v = loadf(stat, n * 6 + (d - 54), bf);
      else if (d < 70)  v = b2f(tt[n * 10 + (d - 60)]);
      xs[r * STR + d] = f2b(sanz(v));
    }
  } else {
    // hsh segment [0,128): canonical bf16 (already sanitized) -> uint4 copy
    for (int idx = tid; idx < 64 * 16; idx += 256) {
      int r = idx >> 4, c = idx & 15;
      uint4 v = ((const uint4*)(hsh + (size_t)(n0 + r) * HID))[c];
      *(uint4*)&xs[r * STR + c * 8] = v;
    }
    constexpr int REM = KP - 128;
    for (int idx = tid; idx < 64 * REM; idx += 256) {
      int r = idx / REM, d = 128 + (idx - r * REM);
      int n = n0 + r;
      float v = 0.f;
      if (d < 155)      v = loadf(nnan, n * 27 + (d - 128), bf);
      else if (d < 156) v = loadf(hgb, n, bf);
      else if (MODE == 2) {
        if (d < 183)      v = loadf(xin, n * 27 + (d - 156), bf);
        else if (d < 189) v = loadf(stat, n * 6 + (d - 183), bf);
        else if (d < 199) v = b2f(tt[n * 10 + (d - 189)]);
      } else {
        if (d < 162)      v = loadf(stat, n * 6 + (d - 156), bf);
        else if (d < 172) v = b2f(tt[n * 10 + (d - 162)]);
      }
      xs[r * STR + d] = f2b(sanz(v));
    }
  }
  __syncthreads();

  const int l  = tid & 63;
  const int wv = tid >> 6;       // wave 0..3
  const int lr = l & 15;
  const int kg = l >> 4;         // 0..3
  const int g0 = wv * 96;

  f32x4 acc[6][4];
#pragma unroll
  for (int mi = 0; mi < 6; mi++) {
    f32x4 bv = *(const f32x4*)&bls[g0 + mi * 16 + kg * 4];
#pragma unroll
    for (int ni = 0; ni < 4; ni++) acc[mi][ni] = bv;
  }

  const ushort* wbase = Wp + (size_t)(g0 + lr) * KP + kg * 8;
#pragma unroll
  for (int ks = 0; ks < KP; ks += 32) {
    bf16x8 av[6], bvv[4];
#pragma unroll
    for (int mi = 0; mi < 6; mi++)
      av[mi] = *(const bf16x8*)(wbase + (size_t)mi * 16 * KP + ks);
#pragma unroll
    for (int ni = 0; ni < 4; ni++)
      bvv[ni] = *(const bf16x8*)&xs[(ni * 16 + lr) * STR + ks + kg * 8];
#pragma unroll
    for (int mi = 0; mi < 6; mi++)
#pragma unroll
      for (int ni = 0; ni < 4; ni++)
        acc[mi][ni] = __builtin_amdgcn_mfma_f32_16x16x32_bf16(
            av[mi], bvv[ni], acc[mi][ni], 0, 0, 0);
  }

#pragma unroll
  for (int ni = 0; ni < 4; ni++) {
    const size_t nrow = (size_t)(n0 + ni * 16 + lr);
    if (gi32) {
      float* gp = (float*)gout + nrow * G3 + g0 + kg * 4;
#pragma unroll
      for (int mi = 0; mi < 6; mi++) *(f32x4*)(gp + mi * 16) = acc[mi][ni];
    } else {
      ushort* gp = (ushort*)gout + nrow * G3 + g0 + kg * 4;
#pragma unroll
      for (int mi = 0; mi < 6; mi++) {
        uint2 pkt;
        pkt.x = (uint)f2b(acc[mi][ni].x) | ((uint)f2b(acc[mi][ni].y) << 16);
        pkt.y = (uint)f2b(acc[mi][ni].z) | ((uint)f2b(acc[mi][ni].w) << 16);
        *(uint2*)(gp + mi * 16) = pkt;
      }
    }
  }
}

// ---------------------------------------------------------------------------
// K3: MFMA batched recurrent scan. 16 sequences per block (C-tile N = seq),
// Whh resident as A-fragments, h as hi+lo bf16 in double-buffered LDS
// (fp32-equivalent recurrence). Wave w owns h-range [32w,32w+32): its 6
// M-tiles are the r/z/n gate rows for THAT h-range, so r,z,n land in the
// same lane/register -> in-register activation, gi folds into acc init,
// ONE barrier per step.
// GRU n-gate: acc_n inits with bhh_n only; gi_n kept in regs:
//   nn = tanh(gi_n + r * (Whh_n h + bhh_n)).
// axis=0: seq = t-lane, step = b (shared GRU). axis=1: seq = b, step = t.
// ---------------------------------------------------------------------------
__global__ void __launch_bounds__(256, 1) scan_mfma_kernel(
    const u64* __restrict__ ptab, const int* __restrict__ flags,
    const void* __restrict__ gi_0, const void* __restrict__ gi_1, int gi32,
    ushort* __restrict__ out_0, ushort* __restrict__ out_1,
    int whh0, int bhh0, int whh1, int bhh1,
    int nsteps, int axis, int bps) {
  __shared__ alignas(16) ushort hbuf[2][2][16][136];  // [buf][hi/lo][seq][k]

  const int bf = flags[0];
  const int tid = threadIdx.x;
  const int sel = (blockIdx.x >= bps) ? 1 : 0;
  const int sb  = sel ? (blockIdx.x - bps) : blockIdx.x;
  const int seq0 = sb * 16;
  const void* Whh = (const void*)ptab[sel ? whh1 : whh0];
  const void* bhh = (const void*)ptab[sel ? bhh1 : bhh0];
  const void* gi  = sel ? gi_1 : gi_0;
  ushort* hout    = sel ? out_1 : out_0;

  const int l  = tid & 63;
  const int wv = tid >> 6;          // 0..3 -> h-range [32wv, 32wv+32)
  const int lr = l & 15;            // seq lane / A-row lane
  const int kg = l >> 4;            // 0..3

  int gb[6];                        // tiles 0,1=r  2,3=z  4,5=n
#pragma unroll
  for (int c = 0; c < 3; c++) {
    gb[2 * c]     = c * 128 + 32 * wv;
    gb[2 * c + 1] = c * 128 + 32 * wv + 16;
  }

  // A-fragments: A[l&15][(l>>4)*8+j] per 16x16x32 K-slice (one-time load)
  bf16x8 av[6][4];
#pragma unroll
  for (int mt = 0; mt < 6; mt++) {
    const int grow = gb[mt] + lr;
#pragma unroll
    for (int ks = 0; ks < 4; ks++) {
#pragma unroll
      for (int j = 0; j < 8; j++)
        av[mt][ks][j] =
            (short)f2b(sanz(loadf(Whh, grow * HID + ks * 32 + kg * 8 + j, bf)));
    }
  }
  // bhh in C-fragment layout: row g = gb[mt] + kg*4 + j
  f32x4 bh4[6];
#pragma unroll
  for (int mt = 0; mt < 6; mt++) {
#pragma unroll
    for (int j = 0; j < 4; j++)
      bh4[mt][j] = sanz(loadf(bhh, gb[mt] + kg * 4 + j, bf));
  }

  for (int i = tid; i < 2 * 16 * 136; i += 256) ((ushort*)hbuf[0])[i] = 0;

  // per-lane streams: n(s) = row0 + s*nstr  (col/seq = seq0 + lr)
  const size_t row0 = axis ? ((size_t)(seq0 + lr) * TLEN) : (size_t)(seq0 + lr);
  const size_t nstr = axis ? 1 : TLEN;
  ushort* hp = hout + row0 * HID + 32 * wv + kg * 4;

  f32x4 gp[6];
  {
    const size_t nb = row0 * G3;
    if (gi32) {
#pragma unroll
      for (int mt = 0; mt < 6; mt++)
        gp[mt] = *(const f32x4*)((const float*)gi + nb + gb[mt] + kg * 4);
    } else {
#pragma unroll
      for (int mt = 0; mt < 6; mt++) {
        uint2 u = *(const uint2*)((const ushort*)gi + nb + gb[mt] + kg * 4);
        f32x4 v;
        v.x = b2f((ushort)(u.x & 0xffffu)); v.y = b2f((ushort)(u.x >> 16));
        v.z = b2f((ushort)(u.y & 0xffffu)); v.w = b2f((ushort)(u.y >> 16));
        gp[mt] = v;
      }
    }
  }

  f32x4 hprev0, hprev1;
#pragma unroll
  for (int j = 0; j < 4; j++) { hprev0[j] = 0.f; hprev1[j] = 0.f; }

  __syncthreads();
  int cur = 0;

#pragma unroll 1
  for (int s = 0; s < nsteps; s++) {
    f32x4 acc[6];
#pragma unroll
    for (int mt = 0; mt < 4; mt++) acc[mt] = gp[mt] + bh4[mt];  // r,z: gi+bhh
    f32x4 gin0 = gp[4], gin1 = gp[5];                            // n: keep gi
    acc[4] = bh4[4];
    acc[5] = bh4[5];

    // prefetch next step's gi (latency hides under MFMA + activation)
    {
      const int sn = (s + 1 < nsteps) ? s + 1 : s;
      const size_t nb = (row0 + (size_t)sn * nstr) * G3;
      if (gi32) {
#pragma unroll
        for (int mt = 0; mt < 6; mt++)
          gp[mt] = *(const f32x4*)((const float*)gi + nb + gb[mt] + kg * 4);
      } else {
#pragma unroll
        for (int mt = 0; mt < 6; mt++) {
          uint2 u = *(const uint2*)((const ushort*)gi + nb + gb[mt] + kg * 4);
          f32x4 v;
          v.x = b2f((ushort)(u.x & 0xffffu)); v.y = b2f((ushort)(u.x >> 16));
          v.z = b2f((ushort)(u.y & 0xffffu)); v.w = b2f((ushort)(u.y >> 16));
          gp[mt] = v;
        }
      }
    }

    // recurrent matvec for 16 seqs: K=128, h = hi + lo
#pragma unroll
    for (int ks = 0; ks < 4; ks++) {
      bf16x8 bhi = *(const bf16x8*)&hbuf[cur][0][lr][ks * 32 + kg * 8];
      bf16x8 blo = *(const bf16x8*)&hbuf[cur][1][lr][ks * 32 + kg * 8];
#pragma unroll
      for (int mt = 0; mt < 6; mt++) {
        acc[mt] = __builtin_amdgcn_mfma_f32_16x16x32_bf16(av[mt][ks], bhi, acc[mt], 0, 0, 0);
        acc[mt] = __builtin_amdgcn_mfma_f32_16x16x32_bf16(av[mt][ks], blo, acc[mt], 0, 0, 0);
      }
    }

    // in-register activation: lane owns (seq = seq0+lr, h = 32wv+16q+kg*4+j)
#pragma unroll
    for (int q = 0; q < 2; q++) {
      f32x4 rr = acc[q], zz = acc[2 + q], np = acc[4 + q];
      f32x4 gq = q ? gin1 : gin0;
      f32x4 hpv = q ? hprev1 : hprev0;
      f32x4 h2;
      u16x4 hi4, lo4, rt4;
#pragma unroll
      for (int j = 0; j < 4; j++) {
        float r  = sigmoidf_(rr[j]);
        float z  = sigmoidf_(zz[j]);
        float nn = tanhf_(gq[j] + r * np[j]);
        float hv = (1.0f - z) * nn + z * hpv[j];
        h2[j] = hv;
        uint hb = __float_as_uint(hv) & 0xffff0000u;
        hi4[j] = (ushort)(hb >> 16);
        lo4[j] = f2b(hv - __uint_as_float(hb));
        rt4[j] = f2b(hv);
      }
      if (q) hprev1 = h2; else hprev0 = h2;
      const int hb0 = 32 * wv + 16 * q + kg * 4;
      *(u16x4*)&hbuf[cur ^ 1][0][lr][hb0] = hi4;
      *(u16x4*)&hbuf[cur ^ 1][1][lr][hb0] = lo4;
      *(u16x4*)(hp + (size_t)s * nstr * HID + 16 * q) = rt4;
    }

    __syncthreads();   // publish hbuf[cur^1]; all reads of hbuf[cur] done above
    cur ^= 1;
  }
}

// ---------------------------------------------------------------------------
// Legacy monolithic kernels — workspace-starved fallback only (tier 4).
// ---------------------------------------------------------------------------
#define SH_DIN  70
#define SH_DINP 72
#define SH_NP4  9

__global__ void __launch_bounds__(G3) shared_gru_kernel(
    const u64* __restrict__ ptab, const int* __restrict__ flags,
    const ushort* __restrict__ tt, ushort* __restrict__ hsh) {
  __shared__ alignas(16) ushort xs[SH_DINP];
  __shared__ alignas(16) ushort hhi[HID];
  __shared__ alignas(16) ushort hlo[HID];
  __shared__ float Ai[G3];
  __shared__ float Ah[G3];

  const int bf = flags[0];
  const void* xin  = (const void*)ptab[0];
  const void* stat = (const void*)ptab[2];
  const void* nnan = (const void*)ptab[3];
  const void* Wih  = (const void*)ptab[8];
  const void* Whh  = (const void*)ptab[9];
  const void* bih  = (const void*)ptab[10];
  const void* bhh  = (const void*)ptab[11];
  const int tid = threadIdx.x;
  const int t = blockIdx.x;

  uint4 wi4[SH_NP4];
#pragma unroll
  for (int c = 0; c < SH_NP4; c++) {
    uint pk[4];
#pragma unroll
    for (int e = 0; e < 4; e++) {
      int p = c * 4 + e;
      uint lo = (2 * p < SH_DIN) ? (uint)f2b(sanz(loadf(Wih, tid * SH_DIN + 2 * p, bf))) : 0u;
      uint hi = (2 * p + 1 < SH_DIN) ? (uint)f2b(sanz(loadf(Wih, tid * SH_DIN + 2 * p + 1, bf))) : 0u;
      pk[e] = lo | (hi << 16);
    }
    wi4[c] = make_uint4(pk[0], pk[1], pk[2], pk[3]);
  }
  uint4 wh4[16];
#pragma unroll
  for (int c = 0; c < 16; c++) {
    uint pk[4];
#pragma unroll
    for (int e = 0; e < 4; e++) {
      int p = c * 4 + e;
      uint lo = (uint)f2b(sanz(loadf(Whh, tid * HID + 2 * p, bf)));
      uint hi = (uint)f2b(sanz(loadf(Whh, tid * HID + 2 * p + 1, bf)));
      pk[e] = lo | (hi << 16);
    }
    wh4[c] = make_uint4(pk[0], pk[1], pk[2], pk[3]);
  }
  const float bi = sanz(loadf(bih, tid, bf));
  const float bh = sanz(loadf(bhh, tid, bf));

  if (tid < HID) { hhi[tid] = 0; hlo[tid] = 0; }
  if (tid >= SH_DIN && tid < SH_DINP) xs[tid] = 0;
  float hprev = 0.0f;
  __syncthreads();

#pragma unroll 1
  for (int b = 0; b < BATCH; b++) {
    const int n = b * TLEN + t;
    if (tid < SH_DIN) {
      float v;
      if (tid < 27)       v = loadf(xin, n * 27 + tid, bf);
      else if (tid < 54)  v = loadf(nnan, n * 27 + (tid - 27), bf);
      else if (tid < 60)  v = loadf(stat, n * 6 + (tid - 54), bf);
      else                v = b2f(tt[n * 10 + (tid - 60)]);
      xs[tid] = f2b(sanz(v));
    }
    __syncthreads();

    float g0 = bi, g1 = 0.0f;
    const uint4* xs4 = (const uint4*)xs;
#pragma unroll
    for (int c = 0; c < SH_NP4; c++) dot2x4(wi4[c], xs4[c], g0, g1);

    float h0 = bh, h1 = 0.0f;
    const uint4* hh4 = (const uint4*)hhi;
    const uint4* hl4 = (const uint4*)hlo;
#pragma unroll
    for (int c = 0; c < 16; c++) {
      dot2x4(wh4[c], hh4[c], h0, h1);
      dot2x4(wh4[c], hl4[c], h0, h1);
    }
    Ai[tid] = g0 + g1;
    Ah[tid] = h0 + h1;
    __syncthreads();

    if (tid < HID) {
      float r = sigmoidf_(Ai[tid] + Ah[tid]);
      float z = sigmoidf_(Ai[HID + tid] + Ah[HID + tid]);
      float nn = tanhf_(Ai[2 * HID + tid] + r * Ah[2 * HID + tid]);
      float h2 = (1.0f - z) * nn + z * hprev;
      hprev = h2;
      hsh[n * HID + tid] = f2b(h2);
      uint hb = __float_as_uint(h2) & 0xffff0000u;
      hhi[tid] = (ushort)(hb >> 16);
      hlo[tid] = f2b(h2 - __uint_as_float(hb));
    }
  }
}

#define T_DINP 200
#define T_NP4  25

__global__ void __launch_bounds__(G3) task_gru_kernel(
    const u64* __restrict__ ptab, const int* __restrict__ flags,
    const ushort* __restrict__ hsh, const ushort* __restrict__ tt,
    ushort* __restrict__ h1o, ushort* __restrict__ h2o) {
  __shared__ alignas(16) ushort xs[T_DINP];
  __shared__ alignas(16) ushort hhi[HID];
  __shared__ alignas(16) ushort hlo[HID];
  __shared__ float Ai[G3];
  __shared__ float Ah[G3];

  const int bf = flags[0];
  const int tid = threadIdx.x;
  const int is2 = (blockIdx.x >= BATCH) ? 1 : 0;
  const int b = blockIdx.x & (BATCH - 1);
  const int DIN = is2 ? 199 : 172;
  const void* xin  = (const void*)ptab[0];
  const void* hgb  = (const void*)ptab[1];
  const void* stat = (const void*)ptab[2];
  const void* nnan = (const void*)ptab[3];
  const void* Wih  = (const void*)ptab[is2 ? 16 : 12];
  const void* Whh  = (const void*)ptab[is2 ? 17 : 13];
  const void* bihp = (const void*)ptab[is2 ? 18 : 14];
  const void* bhhp = (const void*)ptab[is2 ? 19 : 15];
  ushort* hout = is2 ? h2o : h1o;

  uint4 wi4[T_NP4];
#pragma unroll
  for (int c = 0; c < T_NP4; c++) {
    uint pk[4];
#pragma unroll
    for (int e = 0; e < 4; e++) {
      int p = c * 4 + e;
      uint lo = (2 * p < DIN) ? (uint)f2b(sanz(loadf(Wih, tid * DIN + 2 * p, bf))) : 0u;
      uint hi = (2 * p + 1 < DIN) ? (uint)f2b(sanz(loadf(Wih, tid * DIN + 2 * p + 1, bf))) : 0u;
      pk[e] = lo | (hi << 16);
    }
    wi4[c] = make_uint4(pk[0], pk[1], pk[2], pk[3]);
  }
  uint4 wh4[16];
#pragma unroll
  for (int c = 0; c < 16; c++) {
    uint pk[4];
#pragma unroll
    for (int e = 0; e < 4; e++) {
      int p = c * 4 + e;
      uint lo = (uint)f2b(sanz(loadf(Whh, tid * HID + 2 * p, bf)));
      uint hi = (uint)f2b(sanz(loadf(Whh, tid * HID + 2 * p + 1, bf)));
      pk[e] = lo | (hi << 16);
    }
    wh4[c] = make_uint4(pk[0], pk[1], pk[2], pk[3]);
  }
  const float bi = sanz(loadf(bihp, tid, bf));
  const float bh = sanz(loadf(bhhp, tid, bf));

  if (tid < HID) { hhi[tid] = 0; hlo[tid] = 0; }
  if (tid >= DIN && tid < T_DINP) xs[tid] = 0;
  float hprev = 0.0f;
  __syncthreads();

#pragma unroll 1
  for (int t = 0; t < TLEN; t++) {
    const int n = b * TLEN + t;
    if (tid < DIN) {
      float v;
      if (tid < 128)        v = b2f(hsh[n * HID + tid]);
      else if (tid < 155)   v = loadf(nnan, n * 27 + (tid - 128), bf);
      else if (tid < 156)   v = loadf(hgb, n, bf);
      else if (is2) {
        if (tid < 183)      v = loadf(xin, n * 27 + (tid - 156), bf);
        else if (tid < 189) v = loadf(stat, n * 6 + (tid - 183), bf);
        else                v = b2f(tt[n * 10 + (tid - 189)]);
      } else {
        if (tid < 162)      v = loadf(stat, n * 6 + (tid - 156), bf);
        else                v = b2f(tt[n * 10 + (tid - 162)]);
      }
      xs[tid] = f2b(sanz(v));
    }
    __syncthreads();

    float g0 = bi, g1 = 0.0f;
    const uint4* xs4 = (const uint4*)xs;
#pragma unroll
    for (int c = 0; c < T_NP4; c++) dot2x4(wi4[c], xs4[c], g0, g1);

    float h0 = bh, h1 = 0.0f;
    const uint4* hh4 = (const uint4*)hhi;
    const uint4* hl4 = (const uint4*)hlo;
#pragma unroll
    for (int c = 0; c < 16; c++) {
      dot2x4(wh4[c], hh4[c], h0, h1);
      dot2x4(wh4[c], hl4[c], h0, h1);
    }
    Ai[tid] = g0 + g1;
    Ah[tid] = h0 + h1;
    __syncthreads();

    if (tid < HID) {
      float r = sigmoidf_(Ai[tid] + Ah[tid]);
      float z = sigmoidf_(Ai[HID + tid] + Ah[HID + tid]);
      float nn = tanhf_(Ai[2 * HID + tid] + r * Ah[2 * HID + tid]);
      float h2 = (1.0f - z) * nn + z * hprev;
      hprev = h2;
      hout[n * HID + tid] = f2b(h2);
      uint hb = __float_as_uint(h2) & 0xffff0000u;
      hhi[tid] = (ushort)(hb >> 16);
      hlo[tid] = f2b(h2 - __uint_as_float(hb));
    }
  }
}

// ---------------------------------------------------------------------------
// K4: both prefix attentions in ONE launch (512 blocks). FLOAT32 OUTPUT.
// ---------------------------------------------------------------------------
__global__ void __launch_bounds__(128) attn_kernel(
    const u64* __restrict__ ptab, const int* __restrict__ flags,
    const ushort* __restrict__ h1, const ushort* __restrict__ h2,
    float* __restrict__ outp) {
  __shared__ float pl[TLEN];
  __shared__ alignas(16) uint wp[64];
  __shared__ float red[2];

  const int bf = flags[0];
  const int is2 = (blockIdx.x >= BATCH) ? 1 : 0;
  const int b = blockIdx.x & (BATCH - 1);
  const int tid = threadIdx.x;
  const ushort* h = is2 ? h2 : h1;
  const void* w  = (const void*)ptab[is2 ? 22 : 20];
  const void* wb = (const void*)ptab[is2 ? 23 : 21];
  float* out = outp + (size_t)is2 * BT * HID;

  if (tid < 64) {
    uint lo = (uint)f2b(sanz(loadf(w, 2 * tid, bf)));
    uint hi = (uint)f2b(sanz(loadf(w, 2 * tid + 1, bf)));
    wp[tid] = lo | (hi << 16);
  }
  __syncthreads();
  const float wbf = sanz(loadf(wb, 0, bf));

  float e[4];
  const uint4* wp4 = (const uint4*)wp;
#pragma unroll
  for (int q = 0; q < 4; q++) {
    int j = q * 128 + tid;
    const uint4* hr4 = (const uint4*)(h + (size_t)(b * TLEN + j) * HID);
    float a0 = 0.f, a1 = 0.f;
#pragma unroll
    for (int c = 0; c < 16; c++) {
      uint4 hv = hr4[c];
      uint4 wv = wp4[c];
      a0 = dot2(hv.x, wv.x, a0);
      a1 = dot2(hv.y, wv.y, a1);
      a0 = dot2(hv.z, wv.z, a0);
      a1 = dot2(hv.w, wv.w, a1);
    }
    e[q] = a0 + a1 + wbf;
    pl[j] = e[q];
  }
  float m = fmaxf(fmaxf(e[0], e[1]), fmaxf(e[2], e[3]));
#pragma unroll
  for (int off = 32; off > 0; off >>= 1) m = fmaxf(m, __shfl_down(m, off));
  if ((tid & 63) == 0) red[tid >> 6] = m;
  __syncthreads();
  m = fmaxf(red[0], red[1]);
#pragma unroll
  for (int q = 0; q < 4; q++) {
    int j = q * 128 + tid;
    pl[j] = __expf(pl[j] - m);
  }
  __syncthreads();

  float s = 0.f, acc = 0.f;
  const ushort* hc = h + (size_t)b * TLEN * HID + tid;
  float* oc = out + (size_t)b * TLEN * HID + tid;
#pragma unroll 1
  for (int j = 0; j < TLEN; j++) {
    float pj = pl[j];
    s += pj;
    acc = fmaf(pj, b2f(hc[j * HID]), acc);
    oc[j * HID] = __fdividef(acc, fmaxf(s, 1e-37f));
  }
}

// ---------------------------------------------------------------------------
extern "C" void kernel_launch(void* const* d_in, const int* in_sizes, int n_in,
                              void* d_out, int out_size, void* d_ws, size_t ws_size,
                              hipStream_t stream) {
  (void)out_size;
  Tab tab;
  for (int i = 0; i < 24; i++) {
    tab.p[i] = (i < n_in) ? d_in[i] : nullptr;
    tab.sz[i] = (i < n_in) ? in_sizes[i] : -1;
  }

  // ws layout: ptab(192) | flags @192 | @256: wp_sh(73728) | wp_t1(147456) |
  //            wp_t2(172032) | bias(4608) | tt | hsh | h1 | h2 | giA [| giB]
  const size_t WPSH = (size_t)G3 * 96 * 2;    // 73728
  const size_t WPT1 = (size_t)G3 * 192 * 2;   // 147456
  const size_t WPT2 = (size_t)G3 * 224 * 2;   // 172032
  const size_t BIAS = 3 * G3 * 4;             // 4608
  const size_t packo = 256;
  const size_t datao = packo + WPSH + WPT1 + WPT2 + BIAS;  // 398080
  const size_t fixed = datao + (size_t)BT * 10 * 2 + 3ull * BT * HID * 2;
  const size_t gif = (size_t)BT * G3 * 4;   // fp32 gi buffer: 201.3MB
  const size_t gib = (size_t)BT * G3 * 2;   // bf16 gi buffer: 100.7MB
  int tier;
  if      (ws_size >= fixed + 2 * gif) tier = 1;  // fp32 gi, tasks in parallel
  else if (ws_size >= fixed + gif)     tier = 2;  // fp32 gi, tasks serialized
  else if (ws_size >= fixed + gib)     tier = 3;  // bf16 gi, tasks serialized
  else if (ws_size >= fixed)           tier = 4;  // legacy monolithic path
  else return;

  u64* ptab    = (u64*)d_ws;
  int* flags   = (int*)((char*)d_ws + 192);
  ushort* wpsh = (ushort*)((char*)d_ws + packo);
  ushort* wpt1 = (ushort*)((char*)d_ws + packo + WPSH);
  ushort* wpt2 = (ushort*)((char*)d_ws + packo + WPSH + WPT1);
  float* biasb = (float*)((char*)d_ws + packo + WPSH + WPT1 + WPT2);
  ushort* tt   = (ushort*)((char*)d_ws + datao);
  ushort* hsh  = tt + (size_t)BT * 10;
  ushort* h1   = hsh + (size_t)BT * HID;
  ushort* h2   = h1 + (size_t)BT * HID;
  float* out   = (float*)d_out;

  detect_kernel<<<dim3(1), dim3(64), 0, stream>>>(tab, ptab, flags);
  tt_kernel<<<dim3(BT / 256), dim3(256), 0, stream>>>(ptab, flags, tt);

  if (tier == 4) {
    shared_gru_kernel<<<dim3(TLEN), dim3(G3), 0, stream>>>(ptab, flags, tt, hsh);
    task_gru_kernel<<<dim3(2 * BATCH), dim3(G3), 0, stream>>>(ptab, flags, hsh, tt, h1, h2);
    attn_kernel<<<dim3(2 * BATCH), dim3(128), 0, stream>>>(ptab, flags, h1, h2, out);
    return;
  }

  wpack_kernel<<<dim3(48), dim3(256), 0, stream>>>(ptab, flags, wpsh, wpt1, wpt2, biasb);

  const int gi32 = (tier <= 2) ? 1 : 0;
  const size_t esz = gi32 ? 4 : 2;
  char* giA = (char*)d_ws + fixed;
  char* giB = giA + (size_t)BT * G3 * esz;  // valid only in tier 1

  // shared GRU: MFMA gi -> MFMA batched scan over b (16 t-lanes per block)
  gi_mfma_kernel<0><<<dim3(BT / 64), dim3(256), 0, stream>>>(
      ptab, flags, tt, hsh, wpsh, biasb, giA, gi32);
  scan_mfma_kernel<<<dim3(TLEN / 16), dim3(256), 0, stream>>>(
      ptab, flags, giA, giA, gi32, hsh, hsh, 9, 11, 9, 11, BATCH, 0, TLEN / 16);

  if (tier == 1) {
    gi_mfma_kernel<1><<<dim3(BT / 64), dim3(256), 0, stream>>>(
        ptab, flags, tt, hsh, wpt1, biasb, giB, gi32);
    gi_mfma_kernel<2><<<dim3(BT / 64), dim3(256), 0, stream>>>(
        ptab, flags, tt, hsh, wpt2, biasb, giA, gi32);
    scan_mfma_kernel<<<dim3(2 * BATCH / 16), dim3(256), 0, stream>>>(
        ptab, flags, giB, giA, gi32, h1, h2, 13, 15, 17, 19, TLEN, 1, BATCH / 16);
  } else {
    gi_mfma_kernel<1><<<dim3(BT / 64), dim3(256), 0, stream>>>(
        ptab, flags, tt, hsh, wpt1, biasb, giA, gi32);
    scan_mfma_kernel<<<dim3(BATCH / 16), dim3(256), 0, stream>>>(
        ptab, flags, giA, giA, gi32, h1, h1, 13, 15, 13, 15, TLEN, 1, BATCH / 16);
    gi_mfma_kernel<2><<<dim3(BT / 64), dim3(256), 0, stream>>>(
        ptab, flags, tt, hsh, wpt2, biasb, giA, gi32);
    scan_mfma_kernel<<<dim3(BATCH / 16), dim3(256), 0, stream>>>(
        ptab, flags, giA, giA, gi32, h2, h2, 17, 19, 17, 19, TLEN, 1, BATCH / 16);
  }
  attn_kernel<<<dim3(2 * BATCH), dim3(128), 0, stream>>>(ptab, flags, h1, h2, out);
}